// Round 11
// baseline (379.683 us; speedup 1.0000x reference)
//
#include <hip/hip_runtime.h>
#include <hip/hip_fp16.h>

#define N_NODES 50000
#define N_EDGES 800000
#define N_GRAPHS 500
#define DIM 128
#define BN_EPS 1e-5f
#define CAP 64   // fixed per-node edge capacity (Poisson(16); P(deg>64) ~ 1e-20)

// ---- workspace word offsets (4-byte words). End = 13,018,304 w = 52.07 MB
// (proven-safe: ws_size >= 54.6 MB from R5 pass).
#define OFF_XB    0ull          // bf16 x copy        [3.2M words]
#define OFF_A0    3200000ull    // bf16 feat buf A    [3.2M words]
#define OFF_B1    6400000ull    // bf16 feat buf B    [3.2M words]
#define OFF_CUR   9600000ull    // per-node cursor    [N]
#define OFF_GST   9650000ull    // gstart             [G+1]
#define OFF_STATS 9650501ull    // bn stats x2        [512]
#define OFF_MEAN  9651013ull    // pooled mean f32    [G*128]
#define OFF_CSR   9720000ull    // packed bucketed CSR [N*CAP]
#define OFF_WB    12920000ull   // split bf16 weights [3][2][128*128]

typedef unsigned short ushort_t;
typedef unsigned int uint_t;
typedef __attribute__((ext_vector_type(8))) short bf16x8;
typedef __attribute__((ext_vector_type(4))) float f32x4;

__device__ __forceinline__ float bf2f(uint_t u16) {
    return __uint_as_float(u16 << 16);
}
__device__ __forceinline__ ushort_t f2bf(float f) {
    uint_t x = __float_as_uint(f);
    uint_t r = (x + 0x7fffu + ((x >> 16) & 1u)) >> 16;   // round-to-nearest-even
    return (ushort_t)r;
}
__device__ __forceinline__ void unpack8(const uint4 v, float* f) {
    f[0] = bf2f(v.x & 0xffffu); f[1] = bf2f(v.x >> 16);
    f[2] = bf2f(v.y & 0xffffu); f[3] = bf2f(v.y >> 16);
    f[4] = bf2f(v.z & 0xffffu); f[5] = bf2f(v.z >> 16);
    f[6] = bf2f(v.w & 0xffffu); f[7] = bf2f(v.w >> 16);
}
__device__ __forceinline__ uint4 pack8(const float* f) {
    uint4 v;
    v.x = (uint_t)f2bf(f[0]) | ((uint_t)f2bf(f[1]) << 16);
    v.y = (uint_t)f2bf(f[2]) | ((uint_t)f2bf(f[3]) << 16);
    v.z = (uint_t)f2bf(f[4]) | ((uint_t)f2bf(f[5]) << 16);
    v.w = (uint_t)f2bf(f[6]) | ((uint_t)f2bf(f[7]) << 16);
    return v;
}

// ================= fused prep =================
// blocks [0,3125): CSR fill; [3125,6250): x->bf16; [6250,6442): W split;
// [6442,6638): pool boundaries; [6638]: zero stats (BOTH 256-word halves).
#define PREP_FILL_B 3125
#define PREP_XB_B   3125
#define PREP_WS_B   192
#define PREP_BD_B   196
#define PREP_GRID   (PREP_FILL_B + PREP_XB_B + PREP_WS_B + PREP_BD_B + 1)

__global__ __launch_bounds__(256) void prep_kernel(
    const int* __restrict__ ei, const float* __restrict__ ew,
    const float* __restrict__ x, const int* __restrict__ batch,
    const float* __restrict__ W0, const float* __restrict__ W1,
    const float* __restrict__ W2,
    int* __restrict__ cursor, uint_t* __restrict__ csr,
    ushort_t* __restrict__ xb, ushort_t* __restrict__ Wb,
    int* __restrict__ gstart, float* __restrict__ stats) {
    int b = blockIdx.x;
    int tid = threadIdx.x;
    if (b < PREP_FILL_B) {
        int e = b * 256 + tid;
        if (e < N_EDGES) {
            int dst = ei[N_EDGES + e];
            int pos = atomicAdd(&cursor[dst], 1);
            if (pos < CAP) {
                uint_t src = (uint_t)ei[e];
                uint_t wb = (uint_t)__half_as_ushort(__float2half(ew[e]));
                csr[(size_t)dst * CAP + pos] = (src << 16) | wb;
            }
        }
    } else if (b < PREP_FILL_B + PREP_XB_B) {
        int i = (b - PREP_FILL_B) * 256 + tid;
        if (i < N_NODES * DIM / 8) {
            const float* p = x + (size_t)i * 8;
            float f[8];
            float4 a = *reinterpret_cast<const float4*>(p);
            float4 bb = *reinterpret_cast<const float4*>(p + 4);
            f[0]=a.x; f[1]=a.y; f[2]=a.z; f[3]=a.w;
            f[4]=bb.x; f[5]=bb.y; f[6]=bb.z; f[7]=bb.w;
            *reinterpret_cast<uint4*>(xb + (size_t)i * 8) = pack8(f);
        }
    } else if (b < PREP_FILL_B + PREP_XB_B + PREP_WS_B) {
        int i = (b - PREP_FILL_B - PREP_XB_B) * 256 + tid;
        if (i < 3 * DIM * DIM) {
            int layer = i >> 14;
            int idx = i & (DIM * DIM - 1);
            const float* Ws = (layer == 0) ? W0 : (layer == 1) ? W1 : W2;
            float v = Ws[idx];
            ushort_t hi = f2bf(v);
            float rem = v - bf2f((uint_t)hi);
            ushort_t lo = f2bf(rem);
            size_t basew = (size_t)layer * 2 * DIM * DIM;
            Wb[basew + idx] = hi;
            Wb[basew + DIM * DIM + idx] = lo;
        }
    } else if (b < PREP_FILL_B + PREP_XB_B + PREP_WS_B + PREP_BD_B) {
        int i = (b - PREP_FILL_B - PREP_XB_B - PREP_WS_B) * 256 + tid;
        if (i < N_NODES) {
            int bb = batch[i];
            if (i == 0) {
                for (int g = 0; g <= bb; ++g) gstart[g] = 0;
            } else {
                int pb = batch[i - 1];
                for (int g = pb + 1; g <= bb; ++g) gstart[g] = i;
            }
            if (i == N_NODES - 1) {
                for (int g = bb + 1; g <= N_GRAPHS; ++g) gstart[g] = N_NODES;
            }
        }
    } else {
        // zero BOTH stats halves (512 words) with 256 threads
        stats[tid] = 0.0f;
        stats[tid + 256] = 0.0f;
    }
}

// ================= fused layer: gather + BN/ReLU + GEMM + BN stats ==========
// Block = 1024 threads (16 waves) owns 64 dst rows.
// Phase 1: wave w gathers nodes blk*64 + w*4 .. +4 into LDS As (bf16, +8 pad).
//   A[n] = (1+eps)*act(h[n]) + sum_e w_e*act(h[src_e]);
//   act = identity (bn_flag=0) or relu(bn(.)) from raw stats_in.
// Phase 2: MFMA y = A @ W^T + b from LDS; wave = m-tile (w>>2) x 2 n-tiles;
//   W split hi/lo bf16, f32 accum. Fused per-column sum/sumsq -> stats_out.
__global__ __launch_bounds__(1024) void layer_fused_kernel(
    const ushort_t* __restrict__ h, const int* __restrict__ cursor,
    const uint_t* __restrict__ csr, const float* __restrict__ stats_in,
    const float* __restrict__ gamma, const float* __restrict__ beta,
    const float* __restrict__ eps_arr, int layer, int bn_flag, int do_stats,
    const ushort_t* __restrict__ Wb, const float* __restrict__ bias,
    ushort_t* __restrict__ y, float* __restrict__ stats_out) {
    __shared__ ushort_t As[64][136];   // +8 bf16 pad -> <=2-way LDS conflicts
    __shared__ float s_sum[128], s_sq[128];
    const int tid = threadIdx.x;
    const int w = tid >> 6;
    const int lane = tid & 63;
    const int q = lane & 15;
    const int slot = lane >> 4;

    if (tid < 128) { s_sum[tid] = 0.0f; s_sq[tid] = 0.0f; }

    // BN scale/shift for this lane's 8 columns (q*8 .. q*8+7)
    float scale[8], shift[8], floorv;
    if (bn_flag) {
        #pragma unroll
        for (int j = 0; j < 8; ++j) {
            int c = q * 8 + j;
            float mu = stats_in[c] * (1.0f / N_NODES);
            float var = stats_in[128 + c] * (1.0f / N_NODES) - mu * mu;
            float rstd = rsqrtf(var + BN_EPS);
            scale[j] = rstd * gamma[c];
            shift[j] = beta[c] - mu * scale[j];
        }
        floorv = 0.0f;
    } else {
        #pragma unroll
        for (int j = 0; j < 8; ++j) { scale[j] = 1.0f; shift[j] = 0.0f; }
        floorv = -3.0e38f;
    }
    const float epsv = 1.0f + eps_arr[layer];

    // ---- phase 1: gather 4 nodes per wave into LDS ----
    for (int i = 0; i < 4; ++i) {
        int ridx = w * 4 + i;
        int n = blockIdx.x * 64 + ridx;
        float acc[8];
        #pragma unroll
        for (int j = 0; j < 8; ++j) acc[j] = 0.0f;
        if (n < N_NODES) {
            int cnt = cursor[n];
            cnt = (cnt > CAP) ? CAP : cnt;
            int beg = n * CAP;
            int end = beg + cnt;
            int e = beg + slot;
            for (; e + 12 < end; e += 16) {
                uint_t u0 = csr[e], u1 = csr[e + 4], u2 = csr[e + 8], u3 = csr[e + 12];
                int s0 = (int)(u0 >> 16), s1 = (int)(u1 >> 16);
                int s2 = (int)(u2 >> 16), s3 = (int)(u3 >> 16);
                uint4 v0 = *reinterpret_cast<const uint4*>(h + (size_t)s0 * DIM + q * 8);
                uint4 v1 = *reinterpret_cast<const uint4*>(h + (size_t)s1 * DIM + q * 8);
                uint4 v2 = *reinterpret_cast<const uint4*>(h + (size_t)s2 * DIM + q * 8);
                uint4 v3 = *reinterpret_cast<const uint4*>(h + (size_t)s3 * DIM + q * 8);
                float w0 = __half2float(__ushort_as_half((ushort_t)(u0 & 0xffffu)));
                float w1 = __half2float(__ushort_as_half((ushort_t)(u1 & 0xffffu)));
                float w2 = __half2float(__ushort_as_half((ushort_t)(u2 & 0xffffu)));
                float w3 = __half2float(__ushort_as_half((ushort_t)(u3 & 0xffffu)));
                float f0[8], f1[8], f2[8], f3[8];
                unpack8(v0, f0); unpack8(v1, f1); unpack8(v2, f2); unpack8(v3, f3);
                #pragma unroll
                for (int j = 0; j < 8; ++j) {
                    acc[j] += fmaxf(f0[j] * scale[j] + shift[j], floorv) * w0;
                    acc[j] += fmaxf(f1[j] * scale[j] + shift[j], floorv) * w1;
                    acc[j] += fmaxf(f2[j] * scale[j] + shift[j], floorv) * w2;
                    acc[j] += fmaxf(f3[j] * scale[j] + shift[j], floorv) * w3;
                }
            }
            for (; e < end; e += 4) {
                uint_t u = csr[e];
                int s = (int)(u >> 16);
                float ww = __half2float(__ushort_as_half((ushort_t)(u & 0xffffu)));
                uint4 v = *reinterpret_cast<const uint4*>(h + (size_t)s * DIM + q * 8);
                float f[8];
                unpack8(v, f);
                #pragma unroll
                for (int j = 0; j < 8; ++j)
                    acc[j] += fmaxf(f[j] * scale[j] + shift[j], floorv) * ww;
            }
        }
        #pragma unroll
        for (int j = 0; j < 8; ++j) {
            acc[j] += __shfl_xor(acc[j], 16, 64);
            acc[j] += __shfl_xor(acc[j], 32, 64);
        }
        if (slot == 0) {
            float o[8];
            if (n < N_NODES) {
                uint4 hv = *reinterpret_cast<const uint4*>(h + (size_t)n * DIM + q * 8);
                float hf[8];
                unpack8(hv, hf);
                #pragma unroll
                for (int j = 0; j < 8; ++j) {
                    float t = fmaxf(hf[j] * scale[j] + shift[j], floorv);
                    o[j] = epsv * t + acc[j];
                }
            } else {
                #pragma unroll
                for (int j = 0; j < 8; ++j) o[j] = 0.0f;
            }
            *reinterpret_cast<uint4*>(&As[ridx][q * 8]) = pack8(o);
        }
    }
    __syncthreads();

    // ---- phase 2: MFMA GEMM from LDS ----
    const int mt = w >> 2;          // m-tile 0..3
    const int m = q;                // col-in-tile / row-in-tile index
    const int kg = slot;            // k-group 0..3
    bf16x8 afrag[4];
    #pragma unroll
    for (int kc = 0; kc < 4; ++kc)
        afrag[kc] = *reinterpret_cast<const bf16x8*>(&As[mt * 16 + m][kc * 32 + kg * 8]);

    const ushort_t* Whi = Wb;
    const ushort_t* Wlo = Wb + DIM * DIM;
    #pragma unroll
    for (int t2 = 0; t2 < 2; ++t2) {
        const int nt = (w & 3) * 2 + t2;
        const int c = nt * 16 + m;             // output column (B col = lane&15)
        size_t wrow = (size_t)c * DIM + kg * 8;
        f32x4 acc = (f32x4){0.f, 0.f, 0.f, 0.f};
        #pragma unroll
        for (int kc = 0; kc < 4; ++kc) {
            bf16x8 bh = *reinterpret_cast<const bf16x8*>(Whi + wrow + kc * 32);
            acc = __builtin_amdgcn_mfma_f32_16x16x32_bf16(afrag[kc], bh, acc, 0, 0, 0);
            bf16x8 bl = *reinterpret_cast<const bf16x8*>(Wlo + wrow + kc * 32);
            acc = __builtin_amdgcn_mfma_f32_16x16x32_bf16(afrag[kc], bl, acc, 0, 0, 0);
        }
        // C/D: col = lane&15, row = (lane>>4)*4 + reg
        float bv = bias[c];
        float colsum = 0.0f, colsq = 0.0f;
        #pragma unroll
        for (int r = 0; r < 4; ++r) {
            int grow = blockIdx.x * 64 + mt * 16 + kg * 4 + r;
            float val = acc[r] + bv;
            if (grow < N_NODES) {
                y[(size_t)grow * DIM + c] = f2bf(val);
                colsum += val;
                colsq += val * val;
            }
        }
        if (do_stats) {
            colsum += __shfl_xor(colsum, 16, 64);
            colsq  += __shfl_xor(colsq, 16, 64);
            colsum += __shfl_xor(colsum, 32, 64);
            colsq  += __shfl_xor(colsq, 32, 64);
            if (kg == 0) {
                atomicAdd(&s_sum[c], colsum);
                atomicAdd(&s_sq[c], colsq);
            }
        }
    }
    if (do_stats) {
        __syncthreads();
        if (tid < 128) {
            unsafeAtomicAdd(&stats_out[tid], s_sum[tid]);
            unsafeAtomicAdd(&stats_out[128 + tid], s_sq[tid]);
        }
    }
}

// ================= pooling (sorted batch -> segmented mean) =================
__global__ __launch_bounds__(256) void pool_mean_kernel(
    const ushort_t* __restrict__ h, const int* __restrict__ gstart,
    float* __restrict__ mean) {
    __shared__ float sp[16][128];
    int g = blockIdx.x;
    int colg = threadIdx.x & 15;
    int rslot = threadIdx.x >> 4;
    int s = gstart[g], e = gstart[g + 1];
    float acc[8];
    #pragma unroll
    for (int j = 0; j < 8; ++j) acc[j] = 0.0f;
    for (int r = s + rslot; r < e; r += 16) {
        uint4 v = *reinterpret_cast<const uint4*>(h + (size_t)r * DIM + colg * 8);
        float f[8];
        unpack8(v, f);
        #pragma unroll
        for (int j = 0; j < 8; ++j) acc[j] += f[j];
    }
    #pragma unroll
    for (int j = 0; j < 8; ++j) sp[rslot][colg * 8 + j] = acc[j];
    __syncthreads();
    if (threadIdx.x < 128) {
        int c = threadIdx.x;
        float a = 0.0f;
        #pragma unroll
        for (int k = 0; k < 16; ++k) a += sp[k][c];
        mean[(size_t)g * DIM + c] = a / fmaxf((float)(e - s), 1.0f);
    }
}

// ================= final projection =================
__global__ __launch_bounds__(128) void final_kernel(
    const float* __restrict__ mean, const float* __restrict__ Wp,
    const float* __restrict__ bp, float* __restrict__ out) {
    __shared__ float p[128];
    int g = blockIdx.x;
    p[threadIdx.x] = mean[(size_t)g * DIM + threadIdx.x];
    __syncthreads();
    int j = threadIdx.x;
    float acc = bp[j];
    const float* w = Wp + (size_t)j * DIM;
    #pragma unroll
    for (int k = 0; k < DIM; k += 4) {
        float4 wv = *reinterpret_cast<const float4*>(w + k);
        acc += p[k] * wv.x + p[k + 1] * wv.y + p[k + 2] * wv.z + p[k + 3] * wv.w;
    }
    out[(size_t)g * DIM + j] = acc;
}

extern "C" void kernel_launch(void* const* d_in, const int* in_sizes, int n_in,
                              void* d_out, int out_size, void* d_ws, size_t ws_size,
                              hipStream_t stream) {
    const int* ei = (const int*)d_in[0];
    const float* x = (const float*)d_in[1];
    const int* batch = (const int*)d_in[2];
    const float* ew = (const float*)d_in[3];
    const float* W0 = (const float*)d_in[4];
    const float* b0 = (const float*)d_in[5];
    const float* W1 = (const float*)d_in[6];
    const float* b1 = (const float*)d_in[7];
    const float* W2 = (const float*)d_in[8];
    const float* b2 = (const float*)d_in[9];
    const float* eps = (const float*)d_in[10];
    const float* bng = (const float*)d_in[11];
    const float* bnb = (const float*)d_in[12];
    const float* Wp = (const float*)d_in[13];
    const float* bp = (const float*)d_in[14];
    float* out = (float*)d_out;

    float* base = (float*)d_ws;
    ushort_t* XB = (ushort_t*)(base + OFF_XB);
    ushort_t* A0 = (ushort_t*)(base + OFF_A0);
    ushort_t* B1 = (ushort_t*)(base + OFF_B1);
    int* cursor = (int*)(base + OFF_CUR);
    int* gstart = (int*)(base + OFF_GST);
    float* stats0 = base + OFF_STATS;
    float* stats1 = stats0 + 256;
    float* mean = base + OFF_MEAN;
    uint_t* csr = (uint_t*)(base + OFF_CSR);
    ushort_t* Wb = (ushort_t*)(base + OFF_WB);

    const int fusedGrid = (N_NODES + 63) / 64;   // 782
    const size_t wlayer = 2 * DIM * DIM;

    hipMemsetAsync(cursor, 0, N_NODES * sizeof(int), stream);
    prep_kernel<<<PREP_GRID, 256, 0, stream>>>(
        ei, ew, x, batch, W0, W1, W2, cursor, csr, XB, Wb, gstart, stats0);

    // layer 0: in XB (no BN), out A0, stats -> stats0
    layer_fused_kernel<<<fusedGrid, 1024, 0, stream>>>(
        XB, cursor, csr, stats0, bng, bnb, eps, 0, 0, 1,
        Wb, b0, A0, stats0);
    // layer 1: in A0 (BN stats0), out B1, stats -> stats1
    layer_fused_kernel<<<fusedGrid, 1024, 0, stream>>>(
        A0, cursor, csr, stats0, bng, bnb, eps, 1, 1, 1,
        Wb + wlayer, b1, B1, stats1);
    // layer 2: in B1 (BN stats1), out A0, no stats
    layer_fused_kernel<<<fusedGrid, 1024, 0, stream>>>(
        B1, cursor, csr, stats1, bng + DIM, bnb + DIM, eps, 2, 1, 0,
        Wb + 2 * wlayer, b2, A0, stats0);

    pool_mean_kernel<<<N_GRAPHS, 256, 0, stream>>>(A0, gstart, mean);
    final_kernel<<<N_GRAPHS, 128, 0, stream>>>(mean, Wp, bp, out);
}

// Round 12
// 329.396 us; speedup vs baseline: 1.1527x; 1.1527x over previous
//
#include <hip/hip_runtime.h>
#include <hip/hip_fp16.h>

#define N_NODES 50000
#define N_EDGES 800000
#define N_GRAPHS 500
#define DIM 128
#define BN_EPS 1e-5f
#define CAP 64   // fixed per-node edge capacity (Poisson(16); P(deg>64) ~ 1e-20)

// ---- workspace word offsets (4-byte words). End = 13,018,304 w = 52.07 MB
// (proven-safe: ws_size >= 54.6 MB from R5 pass).
#define OFF_XB    0ull          // bf16 x copy        [3.2M words]
#define OFF_A0    3200000ull    // bf16 feat buf A    [3.2M words]
#define OFF_B1    6400000ull    // bf16 feat buf B    [3.2M words]
#define OFF_CUR   9600000ull    // per-node cursor    [N]
#define OFF_GST   9650000ull    // gstart             [G+1]
#define OFF_STATS 9650501ull    // bn stats x2        [512]
#define OFF_MEAN  9651013ull    // (unused now)       [G*128]
#define OFF_CSR   9720000ull    // packed bucketed CSR [N*CAP]
#define OFF_WB    12920000ull   // split bf16 weights [3][2][128*128]

typedef unsigned short ushort_t;
typedef unsigned int uint_t;
typedef __attribute__((ext_vector_type(8))) short bf16x8;
typedef __attribute__((ext_vector_type(4))) float f32x4;

__device__ __forceinline__ float bf2f(uint_t u16) {
    return __uint_as_float(u16 << 16);
}
__device__ __forceinline__ ushort_t f2bf(float f) {
    uint_t x = __float_as_uint(f);
    uint_t r = (x + 0x7fffu + ((x >> 16) & 1u)) >> 16;   // round-to-nearest-even
    return (ushort_t)r;
}
__device__ __forceinline__ void unpack8(const uint4 v, float* f) {
    f[0] = bf2f(v.x & 0xffffu); f[1] = bf2f(v.x >> 16);
    f[2] = bf2f(v.y & 0xffffu); f[3] = bf2f(v.y >> 16);
    f[4] = bf2f(v.z & 0xffffu); f[5] = bf2f(v.z >> 16);
    f[6] = bf2f(v.w & 0xffffu); f[7] = bf2f(v.w >> 16);
}
__device__ __forceinline__ uint4 pack8(const float* f) {
    uint4 v;
    v.x = (uint_t)f2bf(f[0]) | ((uint_t)f2bf(f[1]) << 16);
    v.y = (uint_t)f2bf(f[2]) | ((uint_t)f2bf(f[3]) << 16);
    v.z = (uint_t)f2bf(f[4]) | ((uint_t)f2bf(f[5]) << 16);
    v.w = (uint_t)f2bf(f[6]) | ((uint_t)f2bf(f[7]) << 16);
    return v;
}

// ================= fused prep =================
#define PREP_FILL_B 3125
#define PREP_XB_B   3125
#define PREP_WS_B   192
#define PREP_BD_B   196
#define PREP_GRID   (PREP_FILL_B + PREP_XB_B + PREP_WS_B + PREP_BD_B + 1)

__global__ __launch_bounds__(256) void prep_kernel(
    const int* __restrict__ ei, const float* __restrict__ ew,
    const float* __restrict__ x, const int* __restrict__ batch,
    const float* __restrict__ W0, const float* __restrict__ W1,
    const float* __restrict__ W2,
    int* __restrict__ cursor, uint_t* __restrict__ csr,
    ushort_t* __restrict__ xb, ushort_t* __restrict__ Wb,
    int* __restrict__ gstart, float* __restrict__ stats) {
    int b = blockIdx.x;
    int tid = threadIdx.x;
    if (b < PREP_FILL_B) {
        int e = b * 256 + tid;
        if (e < N_EDGES) {
            int dst = ei[N_EDGES + e];
            int pos = atomicAdd(&cursor[dst], 1);
            if (pos < CAP) {
                uint_t src = (uint_t)ei[e];
                uint_t wb = (uint_t)__half_as_ushort(__float2half(ew[e]));
                csr[(size_t)dst * CAP + pos] = (src << 16) | wb;
            }
        }
    } else if (b < PREP_FILL_B + PREP_XB_B) {
        int i = (b - PREP_FILL_B) * 256 + tid;
        if (i < N_NODES * DIM / 8) {
            const float* p = x + (size_t)i * 8;
            float f[8];
            float4 a = *reinterpret_cast<const float4*>(p);
            float4 bb = *reinterpret_cast<const float4*>(p + 4);
            f[0]=a.x; f[1]=a.y; f[2]=a.z; f[3]=a.w;
            f[4]=bb.x; f[5]=bb.y; f[6]=bb.z; f[7]=bb.w;
            *reinterpret_cast<uint4*>(xb + (size_t)i * 8) = pack8(f);
        }
    } else if (b < PREP_FILL_B + PREP_XB_B + PREP_WS_B) {
        int i = (b - PREP_FILL_B - PREP_XB_B) * 256 + tid;
        if (i < 3 * DIM * DIM) {
            int layer = i >> 14;
            int idx = i & (DIM * DIM - 1);
            const float* Ws = (layer == 0) ? W0 : (layer == 1) ? W1 : W2;
            float v = Ws[idx];
            ushort_t hi = f2bf(v);
            float rem = v - bf2f((uint_t)hi);
            ushort_t lo = f2bf(rem);
            size_t basew = (size_t)layer * 2 * DIM * DIM;
            Wb[basew + idx] = hi;
            Wb[basew + DIM * DIM + idx] = lo;
        }
    } else if (b < PREP_FILL_B + PREP_XB_B + PREP_WS_B + PREP_BD_B) {
        int i = (b - PREP_FILL_B - PREP_XB_B - PREP_WS_B) * 256 + tid;
        if (i < N_NODES) {
            int bb = batch[i];
            if (i == 0) {
                for (int g = 0; g <= bb; ++g) gstart[g] = 0;
            } else {
                int pb = batch[i - 1];
                for (int g = pb + 1; g <= bb; ++g) gstart[g] = i;
            }
            if (i == N_NODES - 1) {
                for (int g = bb + 1; g <= N_GRAPHS; ++g) gstart[g] = N_NODES;
            }
        }
    } else {
        // zero BOTH stats halves (512 words) with 256 threads
        stats[tid] = 0.0f;
        stats[tid + 256] = 0.0f;
    }
}

// ================= fused gather + BN/ReLU + self term (R10, free-running) ===
__global__ __launch_bounds__(256) void aggr_gather_kernel(
    const ushort_t* __restrict__ h, const int* __restrict__ cursor,
    const uint_t* __restrict__ csr, const float* __restrict__ stats,
    const float* __restrict__ gamma, const float* __restrict__ beta,
    const float* __restrict__ eps_arr, int layer, int bn_flag,
    ushort_t* __restrict__ outA) {
    int wid = threadIdx.x >> 6;
    int lane = threadIdx.x & 63;
    int n = blockIdx.x * 4 + wid;
    if (n >= N_NODES) return;
    int q = lane & 15;
    int slot = lane >> 4;

    float scale[8], shift[8], floorv;
    if (bn_flag) {
        #pragma unroll
        for (int j = 0; j < 8; ++j) {
            int c = q * 8 + j;
            float mu = stats[c] * (1.0f / N_NODES);
            float var = stats[128 + c] * (1.0f / N_NODES) - mu * mu;
            float rstd = rsqrtf(var + BN_EPS);
            scale[j] = rstd * gamma[c];
            shift[j] = beta[c] - mu * scale[j];
        }
        floorv = 0.0f;
    } else {
        #pragma unroll
        for (int j = 0; j < 8; ++j) { scale[j] = 1.0f; shift[j] = 0.0f; }
        floorv = -3.0e38f;
    }

    int cnt = cursor[n];
    cnt = (cnt > CAP) ? CAP : cnt;
    int beg = n * CAP;
    int end = beg + cnt;
    float acc[8];
    #pragma unroll
    for (int j = 0; j < 8; ++j) acc[j] = 0.0f;

    int e = beg + slot;
    for (; e + 12 < end; e += 16) {
        uint_t u0 = csr[e], u1 = csr[e + 4], u2 = csr[e + 8], u3 = csr[e + 12];
        int s0 = (int)(u0 >> 16), s1 = (int)(u1 >> 16);
        int s2 = (int)(u2 >> 16), s3 = (int)(u3 >> 16);
        uint4 v0 = *reinterpret_cast<const uint4*>(h + (size_t)s0 * DIM + q * 8);
        uint4 v1 = *reinterpret_cast<const uint4*>(h + (size_t)s1 * DIM + q * 8);
        uint4 v2 = *reinterpret_cast<const uint4*>(h + (size_t)s2 * DIM + q * 8);
        uint4 v3 = *reinterpret_cast<const uint4*>(h + (size_t)s3 * DIM + q * 8);
        float w0 = __half2float(__ushort_as_half((ushort_t)(u0 & 0xffffu)));
        float w1 = __half2float(__ushort_as_half((ushort_t)(u1 & 0xffffu)));
        float w2 = __half2float(__ushort_as_half((ushort_t)(u2 & 0xffffu)));
        float w3 = __half2float(__ushort_as_half((ushort_t)(u3 & 0xffffu)));
        float f0[8], f1[8], f2[8], f3[8];
        unpack8(v0, f0); unpack8(v1, f1); unpack8(v2, f2); unpack8(v3, f3);
        #pragma unroll
        for (int j = 0; j < 8; ++j) {
            acc[j] += fmaxf(f0[j] * scale[j] + shift[j], floorv) * w0;
            acc[j] += fmaxf(f1[j] * scale[j] + shift[j], floorv) * w1;
            acc[j] += fmaxf(f2[j] * scale[j] + shift[j], floorv) * w2;
            acc[j] += fmaxf(f3[j] * scale[j] + shift[j], floorv) * w3;
        }
    }
    for (; e < end; e += 4) {
        uint_t u = csr[e];
        int s = (int)(u >> 16);
        float w = __half2float(__ushort_as_half((ushort_t)(u & 0xffffu)));
        uint4 v = *reinterpret_cast<const uint4*>(h + (size_t)s * DIM + q * 8);
        float f[8];
        unpack8(v, f);
        #pragma unroll
        for (int j = 0; j < 8; ++j)
            acc[j] += fmaxf(f[j] * scale[j] + shift[j], floorv) * w;
    }
    #pragma unroll
    for (int j = 0; j < 8; ++j) {
        acc[j] += __shfl_xor(acc[j], 16, 64);
        acc[j] += __shfl_xor(acc[j], 32, 64);
    }
    if (slot == 0) {
        float epsv = 1.0f + eps_arr[layer];
        uint4 hv = *reinterpret_cast<const uint4*>(h + (size_t)n * DIM + q * 8);
        float hf[8], o[8];
        unpack8(hv, hf);
        #pragma unroll
        for (int j = 0; j < 8; ++j) {
            float t = fmaxf(hf[j] * scale[j] + shift[j], floorv);
            o[j] = epsv * t + acc[j];
        }
        *reinterpret_cast<uint4*>(outA + (size_t)n * DIM + q * 8) = pack8(o);
    }
}

// ================= MFMA GEMM + fused BN stats: y = A @ W^T + b ==============
// W split hi/lo bf16, f32 accum. Block = 64 rows, 4 waves; in-place safe
// (y == A): each wave reads/writes only its own 16-row range.
// do_stats: per-column sum/sumsq of y -> stats_out via shfl + LDS + atomics.
__global__ __launch_bounds__(256) void gin_gemm_mfma_kernel(
    const ushort_t* __restrict__ A, const ushort_t* __restrict__ Wb,
    const float* __restrict__ bias, int do_stats,
    ushort_t* __restrict__ y, float* __restrict__ stats_out) {
    __shared__ float s_sum[128], s_sq[128];
    const int tid = threadIdx.x;
    const int w = tid >> 6;
    const int lane = tid & 63;
    const int m = lane & 15;
    const int kg = lane >> 4;
    const int row = blockIdx.x * 64 + w * 16 + m;
    const bool valid = row < N_NODES;

    if (do_stats) {
        if (tid < 128) { s_sum[tid] = 0.0f; s_sq[tid] = 0.0f; }
        __syncthreads();
    }

    bf16x8 afrag[4];
    #pragma unroll
    for (int kc = 0; kc < 4; ++kc) {
        if (valid) {
            afrag[kc] = *reinterpret_cast<const bf16x8*>(
                A + (size_t)row * DIM + kc * 32 + kg * 8);
        } else {
            bf16x8 z;
            #pragma unroll
            for (int j = 0; j < 8; ++j) z[j] = 0;
            afrag[kc] = z;
        }
    }

    const ushort_t* Whi = Wb;
    const ushort_t* Wlo = Wb + DIM * DIM;
    f32x4 acc[8];
    #pragma unroll
    for (int nt = 0; nt < 8; ++nt) acc[nt] = (f32x4){0.f, 0.f, 0.f, 0.f};

    #pragma unroll
    for (int nt = 0; nt < 8; ++nt) {
        int j = nt * 16 + m;
        size_t wrow = (size_t)j * DIM + kg * 8;
        #pragma unroll
        for (int kc = 0; kc < 4; ++kc) {
            bf16x8 bh = *reinterpret_cast<const bf16x8*>(Whi + wrow + kc * 32);
            acc[nt] = __builtin_amdgcn_mfma_f32_16x16x32_bf16(afrag[kc], bh, acc[nt], 0, 0, 0);
            bf16x8 bl = *reinterpret_cast<const bf16x8*>(Wlo + wrow + kc * 32);
            acc[nt] = __builtin_amdgcn_mfma_f32_16x16x32_bf16(afrag[kc], bl, acc[nt], 0, 0, 0);
        }
    }

    // C/D: col = lane&15, row = (lane>>4)*4 + reg
    const int orow0 = blockIdx.x * 64 + w * 16 + kg * 4;
    #pragma unroll
    for (int nt = 0; nt < 8; ++nt) {
        int c = nt * 16 + m;
        float bv = bias[c];
        float colsum = 0.0f, colsq = 0.0f;
        #pragma unroll
        for (int r = 0; r < 4; ++r) {
            int orow = orow0 + r;
            float val = acc[nt][r] + bv;
            if (orow < N_NODES) {
                y[(size_t)orow * DIM + c] = f2bf(val);
                colsum += val;
                colsq += val * val;
            }
        }
        if (do_stats) {
            // reduce over kg (4 groups x 4 rows = this wave's 16 rows)
            colsum += __shfl_xor(colsum, 16, 64);
            colsq  += __shfl_xor(colsq, 16, 64);
            colsum += __shfl_xor(colsum, 32, 64);
            colsq  += __shfl_xor(colsq, 32, 64);
            if (kg == 0) {
                atomicAdd(&s_sum[c], colsum);
                atomicAdd(&s_sq[c], colsq);
            }
        }
    }
    if (do_stats) {
        __syncthreads();
        if (tid < 128) {
            unsafeAtomicAdd(&stats_out[tid], s_sum[tid]);
            unsafeAtomicAdd(&stats_out[128 + tid], s_sq[tid]);
        }
    }
}

// ================= fused pool (segmented mean) + final projection ===========
__global__ __launch_bounds__(256) void poolfinal_kernel(
    const ushort_t* __restrict__ h, const int* __restrict__ gstart,
    const float* __restrict__ Wp, const float* __restrict__ bp,
    float* __restrict__ out) {
    __shared__ float sp[16][128];
    __shared__ float smean[128];
    int g = blockIdx.x;
    int colg = threadIdx.x & 15;
    int rslot = threadIdx.x >> 4;
    int s = gstart[g], e = gstart[g + 1];
    float acc[8];
    #pragma unroll
    for (int j = 0; j < 8; ++j) acc[j] = 0.0f;
    for (int r = s + rslot; r < e; r += 16) {
        uint4 v = *reinterpret_cast<const uint4*>(h + (size_t)r * DIM + colg * 8);
        float f[8];
        unpack8(v, f);
        #pragma unroll
        for (int j = 0; j < 8; ++j) acc[j] += f[j];
    }
    #pragma unroll
    for (int j = 0; j < 8; ++j) sp[rslot][colg * 8 + j] = acc[j];
    __syncthreads();
    if (threadIdx.x < 128) {
        int c = threadIdx.x;
        float a = 0.0f;
        #pragma unroll
        for (int k = 0; k < 16; ++k) a += sp[k][c];
        smean[c] = a / fmaxf((float)(e - s), 1.0f);
    }
    __syncthreads();
    if (threadIdx.x < 128) {
        int j = threadIdx.x;
        float o = bp[j];
        const float* wrow = Wp + (size_t)j * DIM;
        #pragma unroll
        for (int k = 0; k < DIM; k += 4) {
            float4 wv = *reinterpret_cast<const float4*>(wrow + k);
            o += smean[k] * wv.x + smean[k + 1] * wv.y
               + smean[k + 2] * wv.z + smean[k + 3] * wv.w;
        }
        out[(size_t)g * DIM + j] = o;
    }
}

extern "C" void kernel_launch(void* const* d_in, const int* in_sizes, int n_in,
                              void* d_out, int out_size, void* d_ws, size_t ws_size,
                              hipStream_t stream) {
    const int* ei = (const int*)d_in[0];
    const float* x = (const float*)d_in[1];
    const int* batch = (const int*)d_in[2];
    const float* ew = (const float*)d_in[3];
    const float* W0 = (const float*)d_in[4];
    const float* b0 = (const float*)d_in[5];
    const float* W1 = (const float*)d_in[6];
    const float* b1 = (const float*)d_in[7];
    const float* W2 = (const float*)d_in[8];
    const float* b2 = (const float*)d_in[9];
    const float* eps = (const float*)d_in[10];
    const float* bng = (const float*)d_in[11];
    const float* bnb = (const float*)d_in[12];
    const float* Wp = (const float*)d_in[13];
    const float* bp = (const float*)d_in[14];
    float* out = (float*)d_out;

    float* base = (float*)d_ws;
    ushort_t* XB = (ushort_t*)(base + OFF_XB);
    ushort_t* A0 = (ushort_t*)(base + OFF_A0);
    ushort_t* B1 = (ushort_t*)(base + OFF_B1);
    int* cursor = (int*)(base + OFF_CUR);
    int* gstart = (int*)(base + OFF_GST);
    float* stats0 = base + OFF_STATS;
    float* stats1 = stats0 + 256;
    uint_t* csr = (uint_t*)(base + OFF_CSR);
    ushort_t* Wb = (ushort_t*)(base + OFF_WB);

    const int gatherGrid = (N_NODES + 3) / 4;
    const int mfmaGrid = (N_NODES + 63) / 64;
    const size_t wlayer = 2 * DIM * DIM;

    hipMemsetAsync(cursor, 0, N_NODES * sizeof(int), stream);
    prep_kernel<<<PREP_GRID, 256, 0, stream>>>(
        ei, ew, x, batch, W0, W1, W2, cursor, csr, XB, Wb, gstart, stats0);

    // layer 0 (no BN on input); stats of y -> stats0
    aggr_gather_kernel<<<gatherGrid, 256, 0, stream>>>(
        XB, cursor, csr, nullptr, nullptr, nullptr, eps, 0, 0, A0);
    gin_gemm_mfma_kernel<<<mfmaGrid, 256, 0, stream>>>(A0, Wb, b0, 1, A0, stats0);

    // layer 1 (BN0+ReLU fused into gather); stats of y -> stats1
    aggr_gather_kernel<<<gatherGrid, 256, 0, stream>>>(
        A0, cursor, csr, stats0, bng, bnb, eps, 1, 1, B1);
    gin_gemm_mfma_kernel<<<mfmaGrid, 256, 0, stream>>>(B1, Wb + wlayer, b1, 1, B1, stats1);

    // layer 2 (BN1+ReLU fused into gather); no stats
    aggr_gather_kernel<<<gatherGrid, 256, 0, stream>>>(
        B1, cursor, csr, stats1, bng + DIM, bnb + DIM, eps, 2, 1, A0);
    gin_gemm_mfma_kernel<<<mfmaGrid, 256, 0, stream>>>(A0, Wb + 2 * wlayer, b2, 0, A0, stats0);

    poolfinal_kernel<<<N_GRAPHS, 256, 0, stream>>>(A0, gstart, Wp, bp, out);
}

// Round 13
// 244.433 us; speedup vs baseline: 1.5533x; 1.3476x over previous
//
#include <hip/hip_runtime.h>
#include <hip/hip_fp16.h>

#define N_NODES 50000
#define N_EDGES 800000
#define N_GRAPHS 500
#define DIM 128
#define BN_EPS 1e-5f
#define CAP 64   // fixed per-node edge capacity (Poisson(16); P(deg>64) ~ 1e-20)

// ---- workspace word offsets (4-byte words). End = 13,018,304 w = 52.07 MB
// (proven-safe: ws_size >= 54.6 MB from R5 pass).
#define OFF_XB    0ull          // bf16 x copy        [3.2M words]
#define OFF_A0    3200000ull    // bf16 feat buf A    [3.2M words]
#define OFF_B1    6400000ull    // bf16 feat buf B    [3.2M words]
#define OFF_CUR   9600000ull    // per-node cursor    [N]
#define OFF_GST   9650000ull    // gstart             [G+1]
#define OFF_STATS 9650501ull    // bn stats x2        [512]
#define OFF_CSR   9720000ull    // packed bucketed CSR [N*CAP]
#define OFF_WB    12920000ull   // split bf16 weights [3][2][128*128]

typedef unsigned short ushort_t;
typedef unsigned int uint_t;
typedef __attribute__((ext_vector_type(8))) short bf16x8;
typedef __attribute__((ext_vector_type(4))) float f32x4;

__device__ __forceinline__ float bf2f(uint_t u16) {
    return __uint_as_float(u16 << 16);
}
__device__ __forceinline__ ushort_t f2bf(float f) {
    uint_t x = __float_as_uint(f);
    uint_t r = (x + 0x7fffu + ((x >> 16) & 1u)) >> 16;   // round-to-nearest-even
    return (ushort_t)r;
}
__device__ __forceinline__ void unpack8(const uint4 v, float* f) {
    f[0] = bf2f(v.x & 0xffffu); f[1] = bf2f(v.x >> 16);
    f[2] = bf2f(v.y & 0xffffu); f[3] = bf2f(v.y >> 16);
    f[4] = bf2f(v.z & 0xffffu); f[5] = bf2f(v.z >> 16);
    f[6] = bf2f(v.w & 0xffffu); f[7] = bf2f(v.w >> 16);
}
__device__ __forceinline__ uint4 pack8(const float* f) {
    uint4 v;
    v.x = (uint_t)f2bf(f[0]) | ((uint_t)f2bf(f[1]) << 16);
    v.y = (uint_t)f2bf(f[2]) | ((uint_t)f2bf(f[3]) << 16);
    v.z = (uint_t)f2bf(f[4]) | ((uint_t)f2bf(f[5]) << 16);
    v.w = (uint_t)f2bf(f[6]) | ((uint_t)f2bf(f[7]) << 16);
    return v;
}

// ================= fused prep =================
#define PREP_FILL_B 3125
#define PREP_XB_B   3125
#define PREP_WS_B   192
#define PREP_BD_B   196
#define PREP_GRID   (PREP_FILL_B + PREP_XB_B + PREP_WS_B + PREP_BD_B + 1)

__global__ __launch_bounds__(256) void prep_kernel(
    const int* __restrict__ ei, const float* __restrict__ ew,
    const float* __restrict__ x, const int* __restrict__ batch,
    const float* __restrict__ W0, const float* __restrict__ W1,
    const float* __restrict__ W2,
    int* __restrict__ cursor, uint_t* __restrict__ csr,
    ushort_t* __restrict__ xb, ushort_t* __restrict__ Wb,
    int* __restrict__ gstart, float* __restrict__ stats) {
    int b = blockIdx.x;
    int tid = threadIdx.x;
    if (b < PREP_FILL_B) {
        int e = b * 256 + tid;
        if (e < N_EDGES) {
            int dst = ei[N_EDGES + e];
            int pos = atomicAdd(&cursor[dst], 1);
            if (pos < CAP) {
                uint_t src = (uint_t)ei[e];
                uint_t wb = (uint_t)__half_as_ushort(__float2half(ew[e]));
                csr[(size_t)dst * CAP + pos] = (src << 16) | wb;
            }
        }
    } else if (b < PREP_FILL_B + PREP_XB_B) {
        int i = (b - PREP_FILL_B) * 256 + tid;
        if (i < N_NODES * DIM / 8) {
            const float* p = x + (size_t)i * 8;
            float f[8];
            float4 a = *reinterpret_cast<const float4*>(p);
            float4 bb = *reinterpret_cast<const float4*>(p + 4);
            f[0]=a.x; f[1]=a.y; f[2]=a.z; f[3]=a.w;
            f[4]=bb.x; f[5]=bb.y; f[6]=bb.z; f[7]=bb.w;
            *reinterpret_cast<uint4*>(xb + (size_t)i * 8) = pack8(f);
        }
    } else if (b < PREP_FILL_B + PREP_XB_B + PREP_WS_B) {
        int i = (b - PREP_FILL_B - PREP_XB_B) * 256 + tid;
        if (i < 3 * DIM * DIM) {
            int layer = i >> 14;
            int idx = i & (DIM * DIM - 1);
            const float* Ws = (layer == 0) ? W0 : (layer == 1) ? W1 : W2;
            float v = Ws[idx];
            ushort_t hi = f2bf(v);
            float rem = v - bf2f((uint_t)hi);
            ushort_t lo = f2bf(rem);
            size_t basew = (size_t)layer * 2 * DIM * DIM;
            Wb[basew + idx] = hi;
            Wb[basew + DIM * DIM + idx] = lo;
        }
    } else if (b < PREP_FILL_B + PREP_XB_B + PREP_WS_B + PREP_BD_B) {
        int i = (b - PREP_FILL_B - PREP_XB_B - PREP_WS_B) * 256 + tid;
        if (i < N_NODES) {
            int bb = batch[i];
            if (i == 0) {
                for (int g = 0; g <= bb; ++g) gstart[g] = 0;
            } else {
                int pb = batch[i - 1];
                for (int g = pb + 1; g <= bb; ++g) gstart[g] = i;
            }
            if (i == N_NODES - 1) {
                for (int g = bb + 1; g <= N_GRAPHS; ++g) gstart[g] = N_NODES;
            }
        }
    } else {
        // zero BOTH stats halves (512 words) with 256 threads
        stats[tid] = 0.0f;
        stats[tid + 256] = 0.0f;
    }
}

// ================= fused gather + BN/ReLU + self term (free-running) ========
__global__ __launch_bounds__(256) void aggr_gather_kernel(
    const ushort_t* __restrict__ h, const int* __restrict__ cursor,
    const uint_t* __restrict__ csr, const float* __restrict__ stats,
    const float* __restrict__ gamma, const float* __restrict__ beta,
    const float* __restrict__ eps_arr, int layer, int bn_flag,
    ushort_t* __restrict__ outA) {
    int wid = threadIdx.x >> 6;
    int lane = threadIdx.x & 63;
    int n = blockIdx.x * 4 + wid;
    if (n >= N_NODES) return;
    int q = lane & 15;
    int slot = lane >> 4;

    float scale[8], shift[8], floorv;
    if (bn_flag) {
        #pragma unroll
        for (int j = 0; j < 8; ++j) {
            int c = q * 8 + j;
            float mu = stats[c] * (1.0f / N_NODES);
            float var = stats[128 + c] * (1.0f / N_NODES) - mu * mu;
            float rstd = rsqrtf(var + BN_EPS);
            scale[j] = rstd * gamma[c];
            shift[j] = beta[c] - mu * scale[j];
        }
        floorv = 0.0f;
    } else {
        #pragma unroll
        for (int j = 0; j < 8; ++j) { scale[j] = 1.0f; shift[j] = 0.0f; }
        floorv = -3.0e38f;
    }

    int cnt = cursor[n];
    cnt = (cnt > CAP) ? CAP : cnt;
    int beg = n * CAP;
    int end = beg + cnt;
    float acc[8];
    #pragma unroll
    for (int j = 0; j < 8; ++j) acc[j] = 0.0f;

    int e = beg + slot;
    for (; e + 12 < end; e += 16) {
        uint_t u0 = csr[e], u1 = csr[e + 4], u2 = csr[e + 8], u3 = csr[e + 12];
        int s0 = (int)(u0 >> 16), s1 = (int)(u1 >> 16);
        int s2 = (int)(u2 >> 16), s3 = (int)(u3 >> 16);
        uint4 v0 = *reinterpret_cast<const uint4*>(h + (size_t)s0 * DIM + q * 8);
        uint4 v1 = *reinterpret_cast<const uint4*>(h + (size_t)s1 * DIM + q * 8);
        uint4 v2 = *reinterpret_cast<const uint4*>(h + (size_t)s2 * DIM + q * 8);
        uint4 v3 = *reinterpret_cast<const uint4*>(h + (size_t)s3 * DIM + q * 8);
        float w0 = __half2float(__ushort_as_half((ushort_t)(u0 & 0xffffu)));
        float w1 = __half2float(__ushort_as_half((ushort_t)(u1 & 0xffffu)));
        float w2 = __half2float(__ushort_as_half((ushort_t)(u2 & 0xffffu)));
        float w3 = __half2float(__ushort_as_half((ushort_t)(u3 & 0xffffu)));
        float f0[8], f1[8], f2[8], f3[8];
        unpack8(v0, f0); unpack8(v1, f1); unpack8(v2, f2); unpack8(v3, f3);
        #pragma unroll
        for (int j = 0; j < 8; ++j) {
            acc[j] += fmaxf(f0[j] * scale[j] + shift[j], floorv) * w0;
            acc[j] += fmaxf(f1[j] * scale[j] + shift[j], floorv) * w1;
            acc[j] += fmaxf(f2[j] * scale[j] + shift[j], floorv) * w2;
            acc[j] += fmaxf(f3[j] * scale[j] + shift[j], floorv) * w3;
        }
    }
    for (; e < end; e += 4) {
        uint_t u = csr[e];
        int s = (int)(u >> 16);
        float w = __half2float(__ushort_as_half((ushort_t)(u & 0xffffu)));
        uint4 v = *reinterpret_cast<const uint4*>(h + (size_t)s * DIM + q * 8);
        float f[8];
        unpack8(v, f);
        #pragma unroll
        for (int j = 0; j < 8; ++j)
            acc[j] += fmaxf(f[j] * scale[j] + shift[j], floorv) * w;
    }
    #pragma unroll
    for (int j = 0; j < 8; ++j) {
        acc[j] += __shfl_xor(acc[j], 16, 64);
        acc[j] += __shfl_xor(acc[j], 32, 64);
    }
    if (slot == 0) {
        float epsv = 1.0f + eps_arr[layer];
        uint4 hv = *reinterpret_cast<const uint4*>(h + (size_t)n * DIM + q * 8);
        float hf[8], o[8];
        unpack8(hv, hf);
        #pragma unroll
        for (int j = 0; j < 8; ++j) {
            float t = fmaxf(hf[j] * scale[j] + shift[j], floorv);
            o[j] = epsv * t + acc[j];
        }
        *reinterpret_cast<uint4*>(outA + (size_t)n * DIM + q * 8) = pack8(o);
    }
}

// ================= MFMA GEMM, W staged in LDS (fragment-interleaved) ========
// y = A @ W^T + b; W split hi/lo bf16, f32 accum. Block = 512 thr (8 waves),
// 128 rows; wave w owns m-tile w (its 16 rows only -> in-place safe, y == A).
// Wfrag[part][nt][kc][lane][8]: each ds_read_b128 is lane-consecutive ->
// conflict-free. do_stats: per-column sum/sumsq -> stats_out.
__global__ __launch_bounds__(512) void gin_gemm_mfma_kernel(
    const ushort_t* __restrict__ A, const ushort_t* __restrict__ Wb,
    const float* __restrict__ bias, int do_stats,
    ushort_t* __restrict__ y, float* __restrict__ stats_out) {
    __shared__ ushort_t Wfrag[2][8][4][64][8];   // 64 KB
    __shared__ float s_sum[128], s_sq[128];
    const int tid = threadIdx.x;

    // stage W -> LDS, fragment-interleaved (4096 uint4, 8 per thread)
    #pragma unroll
    for (int s = 0; s < 8; ++s) {
        int idx = tid + s * 512;
        int part = idx >> 11;
        int nt = (idx >> 8) & 7;
        int kc = (idx >> 6) & 3;
        int L = idx & 63;
        int j = nt * 16 + (L & 15);
        int k0 = kc * 32 + (L >> 4) * 8;
        uint4 v = *reinterpret_cast<const uint4*>(
            Wb + (size_t)part * DIM * DIM + (size_t)j * DIM + k0);
        *reinterpret_cast<uint4*>(&Wfrag[part][nt][kc][L][0]) = v;
    }
    if (do_stats && tid < 128) { s_sum[tid] = 0.0f; s_sq[tid] = 0.0f; }
    __syncthreads();

    const int w = tid >> 6;           // wave = m-tile 0..7
    const int lane = tid & 63;
    const int m = lane & 15;
    const int kg = lane >> 4;
    const int row = blockIdx.x * 128 + w * 16 + m;
    const bool valid = row < N_NODES;

    bf16x8 afrag[4];
    #pragma unroll
    for (int kc = 0; kc < 4; ++kc) {
        if (valid) {
            afrag[kc] = *reinterpret_cast<const bf16x8*>(
                A + (size_t)row * DIM + kc * 32 + kg * 8);
        } else {
            bf16x8 z;
            #pragma unroll
            for (int j = 0; j < 8; ++j) z[j] = 0;
            afrag[kc] = z;
        }
    }

    f32x4 acc[8];
    #pragma unroll
    for (int nt = 0; nt < 8; ++nt) acc[nt] = (f32x4){0.f, 0.f, 0.f, 0.f};

    #pragma unroll
    for (int nt = 0; nt < 8; ++nt) {
        #pragma unroll
        for (int kc = 0; kc < 4; ++kc) {
            bf16x8 bh = *reinterpret_cast<const bf16x8*>(&Wfrag[0][nt][kc][lane][0]);
            acc[nt] = __builtin_amdgcn_mfma_f32_16x16x32_bf16(afrag[kc], bh, acc[nt], 0, 0, 0);
            bf16x8 bl = *reinterpret_cast<const bf16x8*>(&Wfrag[1][nt][kc][lane][0]);
            acc[nt] = __builtin_amdgcn_mfma_f32_16x16x32_bf16(afrag[kc], bl, acc[nt], 0, 0, 0);
        }
    }

    // C/D: col = lane&15, row = (lane>>4)*4 + reg
    const int orow0 = blockIdx.x * 128 + w * 16 + kg * 4;
    #pragma unroll
    for (int nt = 0; nt < 8; ++nt) {
        int c = nt * 16 + m;
        float bv = bias[c];
        float colsum = 0.0f, colsq = 0.0f;
        #pragma unroll
        for (int r = 0; r < 4; ++r) {
            int orow = orow0 + r;
            float val = acc[nt][r] + bv;
            if (orow < N_NODES) {
                y[(size_t)orow * DIM + c] = f2bf(val);
                colsum += val;
                colsq += val * val;
            }
        }
        if (do_stats) {
            colsum += __shfl_xor(colsum, 16, 64);
            colsq  += __shfl_xor(colsq, 16, 64);
            colsum += __shfl_xor(colsum, 32, 64);
            colsq  += __shfl_xor(colsq, 32, 64);
            if (kg == 0) {
                atomicAdd(&s_sum[c], colsum);
                atomicAdd(&s_sq[c], colsq);
            }
        }
    }
    if (do_stats) {
        __syncthreads();
        if (tid < 128) {
            unsafeAtomicAdd(&stats_out[tid], s_sum[tid]);
            unsafeAtomicAdd(&stats_out[128 + tid], s_sq[tid]);
        }
    }
}

// ================= fused pool (segmented mean) + final projection ===========
__global__ __launch_bounds__(256) void poolfinal_kernel(
    const ushort_t* __restrict__ h, const int* __restrict__ gstart,
    const float* __restrict__ Wp, const float* __restrict__ bp,
    float* __restrict__ out) {
    __shared__ float sp[16][128];
    __shared__ float smean[128];
    int g = blockIdx.x;
    int colg = threadIdx.x & 15;
    int rslot = threadIdx.x >> 4;
    int s = gstart[g], e = gstart[g + 1];
    float acc[8];
    #pragma unroll
    for (int j = 0; j < 8; ++j) acc[j] = 0.0f;
    for (int r = s + rslot; r < e; r += 16) {
        uint4 v = *reinterpret_cast<const uint4*>(h + (size_t)r * DIM + colg * 8);
        float f[8];
        unpack8(v, f);
        #pragma unroll
        for (int j = 0; j < 8; ++j) acc[j] += f[j];
    }
    #pragma unroll
    for (int j = 0; j < 8; ++j) sp[rslot][colg * 8 + j] = acc[j];
    __syncthreads();
    if (threadIdx.x < 128) {
        int c = threadIdx.x;
        float a = 0.0f;
        #pragma unroll
        for (int k = 0; k < 16; ++k) a += sp[k][c];
        smean[c] = a / fmaxf((float)(e - s), 1.0f);
    }
    __syncthreads();
    if (threadIdx.x < 128) {
        int j = threadIdx.x;
        float o = bp[j];
        const float* wrow = Wp + (size_t)j * DIM;
        #pragma unroll
        for (int k = 0; k < DIM; k += 4) {
            float4 wv = *reinterpret_cast<const float4*>(wrow + k);
            o += smean[k] * wv.x + smean[k + 1] * wv.y
               + smean[k + 2] * wv.z + smean[k + 3] * wv.w;
        }
        out[(size_t)g * DIM + j] = o;
    }
}

extern "C" void kernel_launch(void* const* d_in, const int* in_sizes, int n_in,
                              void* d_out, int out_size, void* d_ws, size_t ws_size,
                              hipStream_t stream) {
    const int* ei = (const int*)d_in[0];
    const float* x = (const float*)d_in[1];
    const int* batch = (const int*)d_in[2];
    const float* ew = (const float*)d_in[3];
    const float* W0 = (const float*)d_in[4];
    const float* b0 = (const float*)d_in[5];
    const float* W1 = (const float*)d_in[6];
    const float* b1 = (const float*)d_in[7];
    const float* W2 = (const float*)d_in[8];
    const float* b2 = (const float*)d_in[9];
    const float* eps = (const float*)d_in[10];
    const float* bng = (const float*)d_in[11];
    const float* bnb = (const float*)d_in[12];
    const float* Wp = (const float*)d_in[13];
    const float* bp = (const float*)d_in[14];
    float* out = (float*)d_out;

    float* base = (float*)d_ws;
    ushort_t* XB = (ushort_t*)(base + OFF_XB);
    ushort_t* A0 = (ushort_t*)(base + OFF_A0);
    ushort_t* B1 = (ushort_t*)(base + OFF_B1);
    int* cursor = (int*)(base + OFF_CUR);
    int* gstart = (int*)(base + OFF_GST);
    float* stats0 = base + OFF_STATS;
    float* stats1 = stats0 + 256;
    uint_t* csr = (uint_t*)(base + OFF_CSR);
    ushort_t* Wb = (ushort_t*)(base + OFF_WB);

    const int gatherGrid = (N_NODES + 3) / 4;
    const int mfmaGrid = (N_NODES + 127) / 128;   // 391 blocks x 512 threads
    const size_t wlayer = 2 * DIM * DIM;

    hipMemsetAsync(cursor, 0, N_NODES * sizeof(int), stream);
    prep_kernel<<<PREP_GRID, 256, 0, stream>>>(
        ei, ew, x, batch, W0, W1, W2, cursor, csr, XB, Wb, gstart, stats0);

    // layer 0 (no BN on input); stats of y -> stats0
    aggr_gather_kernel<<<gatherGrid, 256, 0, stream>>>(
        XB, cursor, csr, nullptr, nullptr, nullptr, eps, 0, 0, A0);
    gin_gemm_mfma_kernel<<<mfmaGrid, 512, 0, stream>>>(A0, Wb, b0, 1, A0, stats0);

    // layer 1 (BN0+ReLU fused into gather); stats of y -> stats1
    aggr_gather_kernel<<<gatherGrid, 256, 0, stream>>>(
        A0, cursor, csr, stats0, bng, bnb, eps, 1, 1, B1);
    gin_gemm_mfma_kernel<<<mfmaGrid, 512, 0, stream>>>(B1, Wb + wlayer, b1, 1, B1, stats1);

    // layer 2 (BN1+ReLU fused into gather); no stats
    aggr_gather_kernel<<<gatherGrid, 256, 0, stream>>>(
        B1, cursor, csr, stats1, bng + DIM, bnb + DIM, eps, 2, 1, A0);
    gin_gemm_mfma_kernel<<<mfmaGrid, 512, 0, stream>>>(A0, Wb + 2 * wlayer, b2, 0, A0, stats0);

    poolfinal_kernel<<<N_GRAPHS, 256, 0, stream>>>(A0, gstart, Wp, bp, out);
}

// Round 14
// 242.340 us; speedup vs baseline: 1.5667x; 1.0086x over previous
//
#include <hip/hip_runtime.h>
#include <hip/hip_fp16.h>

#define N_NODES 50000
#define N_EDGES 800000
#define N_GRAPHS 500
#define DIM 128
#define BN_EPS 1e-5f
#define CAP 64   // fixed per-node edge capacity (Poisson(16); P(deg>64) ~ 1e-20)

// ---- workspace word offsets (4-byte words). End = 12,969,152 w = 51.88 MB
// (proven-safe: ws_size >= 54.6 MB from R5 pass).
#define OFF_XB    0ull          // bf16 x copy        [3.2M words]
#define OFF_A0    3200000ull    // bf16 feat buf A    [3.2M words]
#define OFF_B1    6400000ull    // bf16 feat buf B    [3.2M words]
#define OFF_CUR   9600000ull    // per-node cursor    [N]
#define OFF_GST   9650000ull    // gstart             [G+1]
#define OFF_STATS 9650501ull    // bn stats x2        [512]
#define OFF_CSR   9720000ull    // packed bucketed CSR [N*CAP]
#define OFF_WB    12920000ull   // bf16 weights [3][128*128]

typedef unsigned short ushort_t;
typedef unsigned int uint_t;
typedef __attribute__((ext_vector_type(8))) short bf16x8;
typedef __attribute__((ext_vector_type(4))) float f32x4;

__device__ __forceinline__ float bf2f(uint_t u16) {
    return __uint_as_float(u16 << 16);
}
__device__ __forceinline__ ushort_t f2bf(float f) {
    uint_t x = __float_as_uint(f);
    uint_t r = (x + 0x7fffu + ((x >> 16) & 1u)) >> 16;   // round-to-nearest-even
    return (ushort_t)r;
}
__device__ __forceinline__ void unpack8(const uint4 v, float* f) {
    f[0] = bf2f(v.x & 0xffffu); f[1] = bf2f(v.x >> 16);
    f[2] = bf2f(v.y & 0xffffu); f[3] = bf2f(v.y >> 16);
    f[4] = bf2f(v.z & 0xffffu); f[5] = bf2f(v.z >> 16);
    f[6] = bf2f(v.w & 0xffffu); f[7] = bf2f(v.w >> 16);
}
__device__ __forceinline__ uint4 pack8(const float* f) {
    uint4 v;
    v.x = (uint_t)f2bf(f[0]) | ((uint_t)f2bf(f[1]) << 16);
    v.y = (uint_t)f2bf(f[2]) | ((uint_t)f2bf(f[3]) << 16);
    v.z = (uint_t)f2bf(f[4]) | ((uint_t)f2bf(f[5]) << 16);
    v.w = (uint_t)f2bf(f[6]) | ((uint_t)f2bf(f[7]) << 16);
    return v;
}

// ================= fused prep =================
// blocks [0,3125): CSR fill (slot-interleaved pos); [3125,6250): x->bf16;
// [6250,6442): W->bf16; [6442,6638): pool boundaries; [6638]: zero stats.
#define PREP_FILL_B 3125
#define PREP_XB_B   3125
#define PREP_WS_B   192
#define PREP_BD_B   196
#define PREP_GRID   (PREP_FILL_B + PREP_XB_B + PREP_WS_B + PREP_BD_B + 1)

__global__ __launch_bounds__(256) void prep_kernel(
    const int* __restrict__ ei, const float* __restrict__ ew,
    const float* __restrict__ x, const int* __restrict__ batch,
    const float* __restrict__ W0, const float* __restrict__ W1,
    const float* __restrict__ W2,
    int* __restrict__ cursor, uint_t* __restrict__ csr,
    ushort_t* __restrict__ xb, ushort_t* __restrict__ Wb,
    int* __restrict__ gstart, float* __restrict__ stats) {
    int b = blockIdx.x;
    int tid = threadIdx.x;
    if (b < PREP_FILL_B) {
        int e = b * 256 + tid;
        if (e < N_EDGES) {
            int dst = ei[N_EDGES + e];
            int pos = atomicAdd(&cursor[dst], 1);
            if (pos < CAP) {
                // slot-interleaved remap: slot s = pos&3 owns contiguous
                // [s*16, s*16+16) so gather can uint4-load its 4 entries.
                int rpos = (pos & 3) * 16 + (pos >> 2);
                uint_t src = (uint_t)ei[e];
                uint_t wb = (uint_t)__half_as_ushort(__float2half(ew[e]));
                csr[(size_t)dst * CAP + rpos] = (src << 16) | wb;
            }
        }
    } else if (b < PREP_FILL_B + PREP_XB_B) {
        int i = (b - PREP_FILL_B) * 256 + tid;
        if (i < N_NODES * DIM / 8) {
            const float* p = x + (size_t)i * 8;
            float f[8];
            float4 a = *reinterpret_cast<const float4*>(p);
            float4 bb = *reinterpret_cast<const float4*>(p + 4);
            f[0]=a.x; f[1]=a.y; f[2]=a.z; f[3]=a.w;
            f[4]=bb.x; f[5]=bb.y; f[6]=bb.z; f[7]=bb.w;
            *reinterpret_cast<uint4*>(xb + (size_t)i * 8) = pack8(f);
        }
    } else if (b < PREP_FILL_B + PREP_XB_B + PREP_WS_B) {
        int i = (b - PREP_FILL_B - PREP_XB_B) * 256 + tid;
        if (i < 3 * DIM * DIM) {
            int layer = i >> 14;
            int idx = i & (DIM * DIM - 1);
            const float* Ws = (layer == 0) ? W0 : (layer == 1) ? W1 : W2;
            Wb[(size_t)layer * DIM * DIM + idx] = f2bf(Ws[idx]);
        }
    } else if (b < PREP_FILL_B + PREP_XB_B + PREP_WS_B + PREP_BD_B) {
        int i = (b - PREP_FILL_B - PREP_XB_B - PREP_WS_B) * 256 + tid;
        if (i < N_NODES) {
            int bb = batch[i];
            if (i == 0) {
                for (int g = 0; g <= bb; ++g) gstart[g] = 0;
            } else {
                int pb = batch[i - 1];
                for (int g = pb + 1; g <= bb; ++g) gstart[g] = i;
            }
            if (i == N_NODES - 1) {
                for (int g = bb + 1; g <= N_GRAPHS; ++g) gstart[g] = N_NODES;
            }
        }
    } else {
        // zero BOTH stats halves (512 words) with 256 threads
        stats[tid] = 0.0f;
        stats[tid + 256] = 0.0f;
    }
}

// ================= fused gather + BN/ReLU + self term (free-running) ========
// One wave per dst: 4 edge slots x 16 lanes x 8 bf16. Slot s's edges are
// contiguous at bucket + s*16 (fill remap) -> uint4 csr loads.
__global__ __launch_bounds__(256) void aggr_gather_kernel(
    const ushort_t* __restrict__ h, const int* __restrict__ cursor,
    const uint_t* __restrict__ csr, const float* __restrict__ stats,
    const float* __restrict__ gamma, const float* __restrict__ beta,
    const float* __restrict__ eps_arr, int layer, int bn_flag,
    ushort_t* __restrict__ outA) {
    int wid = threadIdx.x >> 6;
    int lane = threadIdx.x & 63;
    int n = blockIdx.x * 4 + wid;
    if (n >= N_NODES) return;
    int q = lane & 15;
    int slot = lane >> 4;

    float scale[8], shift[8], floorv;
    if (bn_flag) {
        #pragma unroll
        for (int j = 0; j < 8; ++j) {
            int c = q * 8 + j;
            float mu = stats[c] * (1.0f / N_NODES);
            float var = stats[128 + c] * (1.0f / N_NODES) - mu * mu;
            float rstd = rsqrtf(var + BN_EPS);
            scale[j] = rstd * gamma[c];
            shift[j] = beta[c] - mu * scale[j];
        }
        floorv = 0.0f;
    } else {
        #pragma unroll
        for (int j = 0; j < 8; ++j) { scale[j] = 1.0f; shift[j] = 0.0f; }
        floorv = -3.0e38f;
    }

    int cnt = cursor[n];
    cnt = (cnt > CAP) ? CAP : cnt;
    int cnt_s = (cnt + 3 - slot) >> 2;            // this slot's entry count
    const uint_t* mycsr = csr + (size_t)n * CAP + slot * 16;
    float acc[8];
    #pragma unroll
    for (int j = 0; j < 8; ++j) acc[j] = 0.0f;

    int i = 0;
    for (; i + 4 <= cnt_s; i += 4) {
        uint4 u4 = *reinterpret_cast<const uint4*>(mycsr + i);
        int s0 = (int)(u4.x >> 16), s1 = (int)(u4.y >> 16);
        int s2 = (int)(u4.z >> 16), s3 = (int)(u4.w >> 16);
        uint4 v0 = *reinterpret_cast<const uint4*>(h + (size_t)s0 * DIM + q * 8);
        uint4 v1 = *reinterpret_cast<const uint4*>(h + (size_t)s1 * DIM + q * 8);
        uint4 v2 = *reinterpret_cast<const uint4*>(h + (size_t)s2 * DIM + q * 8);
        uint4 v3 = *reinterpret_cast<const uint4*>(h + (size_t)s3 * DIM + q * 8);
        float w0 = __half2float(__ushort_as_half((ushort_t)(u4.x & 0xffffu)));
        float w1 = __half2float(__ushort_as_half((ushort_t)(u4.y & 0xffffu)));
        float w2 = __half2float(__ushort_as_half((ushort_t)(u4.z & 0xffffu)));
        float w3 = __half2float(__ushort_as_half((ushort_t)(u4.w & 0xffffu)));
        float f0[8], f1[8], f2[8], f3[8];
        unpack8(v0, f0); unpack8(v1, f1); unpack8(v2, f2); unpack8(v3, f3);
        #pragma unroll
        for (int j = 0; j < 8; ++j) {
            acc[j] += fmaxf(f0[j] * scale[j] + shift[j], floorv) * w0;
            acc[j] += fmaxf(f1[j] * scale[j] + shift[j], floorv) * w1;
            acc[j] += fmaxf(f2[j] * scale[j] + shift[j], floorv) * w2;
            acc[j] += fmaxf(f3[j] * scale[j] + shift[j], floorv) * w3;
        }
    }
    for (; i < cnt_s; ++i) {
        uint_t u = mycsr[i];
        int s = (int)(u >> 16);
        float w = __half2float(__ushort_as_half((ushort_t)(u & 0xffffu)));
        uint4 v = *reinterpret_cast<const uint4*>(h + (size_t)s * DIM + q * 8);
        float f[8];
        unpack8(v, f);
        #pragma unroll
        for (int j = 0; j < 8; ++j)
            acc[j] += fmaxf(f[j] * scale[j] + shift[j], floorv) * w;
    }
    #pragma unroll
    for (int j = 0; j < 8; ++j) {
        acc[j] += __shfl_xor(acc[j], 16, 64);
        acc[j] += __shfl_xor(acc[j], 32, 64);
    }
    if (slot == 0) {
        float epsv = 1.0f + eps_arr[layer];
        uint4 hv = *reinterpret_cast<const uint4*>(h + (size_t)n * DIM + q * 8);
        float hf[8], o[8];
        unpack8(hv, hf);
        #pragma unroll
        for (int j = 0; j < 8; ++j) {
            float t = fmaxf(hf[j] * scale[j] + shift[j], floorv);
            o[j] = epsv * t + acc[j];
        }
        *reinterpret_cast<uint4*>(outA + (size_t)n * DIM + q * 8) = pack8(o);
    }
}

// ================= MFMA GEMM, W staged in LDS (fragment-interleaved) ========
// y = A @ W^T + b; single bf16 W, f32 accum. Block = 512 thr (8 waves),
// 128 rows; wave w owns m-tile w (its 16 rows only -> in-place safe, y == A).
// Wfrag[nt][kc][lane][8]: each ds_read_b128 is lane-consecutive -> no bank
// conflicts. do_stats: per-column sum/sumsq -> stats_out.
__global__ __launch_bounds__(512) void gin_gemm_mfma_kernel(
    const ushort_t* __restrict__ A, const ushort_t* __restrict__ Wb,
    const float* __restrict__ bias, int do_stats,
    ushort_t* __restrict__ y, float* __restrict__ stats_out) {
    __shared__ ushort_t Wfrag[8][4][64][8];   // 32 KB
    __shared__ float s_sum[128], s_sq[128];
    const int tid = threadIdx.x;

    // stage W -> LDS, fragment-interleaved (2048 uint4, 4 per thread)
    #pragma unroll
    for (int s = 0; s < 4; ++s) {
        int idx = tid + s * 512;
        int nt = idx >> 8;
        int kc = (idx >> 6) & 3;
        int L = idx & 63;
        int j = nt * 16 + (L & 15);
        int k0 = kc * 32 + (L >> 4) * 8;
        uint4 v = *reinterpret_cast<const uint4*>(Wb + (size_t)j * DIM + k0);
        *reinterpret_cast<uint4*>(&Wfrag[nt][kc][L][0]) = v;
    }
    if (do_stats && tid < 128) { s_sum[tid] = 0.0f; s_sq[tid] = 0.0f; }
    __syncthreads();

    const int w = tid >> 6;           // wave = m-tile 0..7
    const int lane = tid & 63;
    const int m = lane & 15;
    const int kg = lane >> 4;
    const int row = blockIdx.x * 128 + w * 16 + m;
    const bool valid = row < N_NODES;

    bf16x8 afrag[4];
    #pragma unroll
    for (int kc = 0; kc < 4; ++kc) {
        if (valid) {
            afrag[kc] = *reinterpret_cast<const bf16x8*>(
                A + (size_t)row * DIM + kc * 32 + kg * 8);
        } else {
            bf16x8 z;
            #pragma unroll
            for (int j = 0; j < 8; ++j) z[j] = 0;
            afrag[kc] = z;
        }
    }

    f32x4 acc[8];
    #pragma unroll
    for (int nt = 0; nt < 8; ++nt) acc[nt] = (f32x4){0.f, 0.f, 0.f, 0.f};

    #pragma unroll
    for (int nt = 0; nt < 8; ++nt) {
        #pragma unroll
        for (int kc = 0; kc < 4; ++kc) {
            bf16x8 bh = *reinterpret_cast<const bf16x8*>(&Wfrag[nt][kc][lane][0]);
            acc[nt] = __builtin_amdgcn_mfma_f32_16x16x32_bf16(afrag[kc], bh, acc[nt], 0, 0, 0);
        }
    }

    // C/D: col = lane&15, row = (lane>>4)*4 + reg
    const int orow0 = blockIdx.x * 128 + w * 16 + kg * 4;
    #pragma unroll
    for (int nt = 0; nt < 8; ++nt) {
        int c = nt * 16 + m;
        float bv = bias[c];
        float colsum = 0.0f, colsq = 0.0f;
        #pragma unroll
        for (int r = 0; r < 4; ++r) {
            int orow = orow0 + r;
            float val = acc[nt][r] + bv;
            if (orow < N_NODES) {
                y[(size_t)orow * DIM + c] = f2bf(val);
                colsum += val;
                colsq += val * val;
            }
        }
        if (do_stats) {
            colsum += __shfl_xor(colsum, 16, 64);
            colsq  += __shfl_xor(colsq, 16, 64);
            colsum += __shfl_xor(colsum, 32, 64);
            colsq  += __shfl_xor(colsq, 32, 64);
            if (kg == 0) {
                atomicAdd(&s_sum[c], colsum);
                atomicAdd(&s_sq[c], colsq);
            }
        }
    }
    if (do_stats) {
        __syncthreads();
        if (tid < 128) {
            unsafeAtomicAdd(&stats_out[tid], s_sum[tid]);
            unsafeAtomicAdd(&stats_out[128 + tid], s_sq[tid]);
        }
    }
}

// ================= fused pool (segmented mean) + final projection ===========
__global__ __launch_bounds__(256) void poolfinal_kernel(
    const ushort_t* __restrict__ h, const int* __restrict__ gstart,
    const float* __restrict__ Wp, const float* __restrict__ bp,
    float* __restrict__ out) {
    __shared__ float sp[16][128];
    __shared__ float smean[128];
    int g = blockIdx.x;
    int colg = threadIdx.x & 15;
    int rslot = threadIdx.x >> 4;
    int s = gstart[g], e = gstart[g + 1];
    float acc[8];
    #pragma unroll
    for (int j = 0; j < 8; ++j) acc[j] = 0.0f;
    for (int r = s + rslot; r < e; r += 16) {
        uint4 v = *reinterpret_cast<const uint4*>(h + (size_t)r * DIM + colg * 8);
        float f[8];
        unpack8(v, f);
        #pragma unroll
        for (int j = 0; j < 8; ++j) acc[j] += f[j];
    }
    #pragma unroll
    for (int j = 0; j < 8; ++j) sp[rslot][colg * 8 + j] = acc[j];
    __syncthreads();
    if (threadIdx.x < 128) {
        int c = threadIdx.x;
        float a = 0.0f;
        #pragma unroll
        for (int k = 0; k < 16; ++k) a += sp[k][c];
        smean[c] = a / fmaxf((float)(e - s), 1.0f);
    }
    __syncthreads();
    if (threadIdx.x < 128) {
        int j = threadIdx.x;
        float o = bp[j];
        const float* wrow = Wp + (size_t)j * DIM;
        #pragma unroll
        for (int k = 0; k < DIM; k += 4) {
            float4 wv = *reinterpret_cast<const float4*>(wrow + k);
            o += smean[k] * wv.x + smean[k + 1] * wv.y
               + smean[k + 2] * wv.z + smean[k + 3] * wv.w;
        }
        out[(size_t)g * DIM + j] = o;
    }
}

extern "C" void kernel_launch(void* const* d_in, const int* in_sizes, int n_in,
                              void* d_out, int out_size, void* d_ws, size_t ws_size,
                              hipStream_t stream) {
    const int* ei = (const int*)d_in[0];
    const float* x = (const float*)d_in[1];
    const int* batch = (const int*)d_in[2];
    const float* ew = (const float*)d_in[3];
    const float* W0 = (const float*)d_in[4];
    const float* b0 = (const float*)d_in[5];
    const float* W1 = (const float*)d_in[6];
    const float* b1 = (const float*)d_in[7];
    const float* W2 = (const float*)d_in[8];
    const float* b2 = (const float*)d_in[9];
    const float* eps = (const float*)d_in[10];
    const float* bng = (const float*)d_in[11];
    const float* bnb = (const float*)d_in[12];
    const float* Wp = (const float*)d_in[13];
    const float* bp = (const float*)d_in[14];
    float* out = (float*)d_out;

    float* base = (float*)d_ws;
    ushort_t* XB = (ushort_t*)(base + OFF_XB);
    ushort_t* A0 = (ushort_t*)(base + OFF_A0);
    ushort_t* B1 = (ushort_t*)(base + OFF_B1);
    int* cursor = (int*)(base + OFF_CUR);
    int* gstart = (int*)(base + OFF_GST);
    float* stats0 = base + OFF_STATS;
    float* stats1 = stats0 + 256;
    uint_t* csr = (uint_t*)(base + OFF_CSR);
    ushort_t* Wb = (ushort_t*)(base + OFF_WB);

    const int gatherGrid = (N_NODES + 3) / 4;
    const int mfmaGrid = (N_NODES + 127) / 128;   // 391 blocks x 512 threads
    const size_t wlayer = (size_t)DIM * DIM;

    hipMemsetAsync(cursor, 0, N_NODES * sizeof(int), stream);
    prep_kernel<<<PREP_GRID, 256, 0, stream>>>(
        ei, ew, x, batch, W0, W1, W2, cursor, csr, XB, Wb, gstart, stats0);

    // layer 0 (no BN on input); stats of y -> stats0
    aggr_gather_kernel<<<gatherGrid, 256, 0, stream>>>(
        XB, cursor, csr, nullptr, nullptr, nullptr, eps, 0, 0, A0);
    gin_gemm_mfma_kernel<<<mfmaGrid, 512, 0, stream>>>(A0, Wb, b0, 1, A0, stats0);

    // layer 1 (BN0+ReLU fused into gather); stats of y -> stats1
    aggr_gather_kernel<<<gatherGrid, 256, 0, stream>>>(
        A0, cursor, csr, stats0, bng, bnb, eps, 1, 1, B1);
    gin_gemm_mfma_kernel<<<mfmaGrid, 512, 0, stream>>>(B1, Wb + wlayer, b1, 1, B1, stats1);

    // layer 2 (BN1+ReLU fused into gather); no stats
    aggr_gather_kernel<<<gatherGrid, 256, 0, stream>>>(
        B1, cursor, csr, stats1, bng + DIM, bnb + DIM, eps, 2, 1, A0);
    gin_gemm_mfma_kernel<<<mfmaGrid, 512, 0, stream>>>(A0, Wb + 2 * wlayer, b2, 0, A0, stats0);

    poolfinal_kernel<<<N_GRAPHS, 256, 0, stream>>>(A0, gstart, Wp, bp, out);
}

// Round 15
// 234.536 us; speedup vs baseline: 1.6189x; 1.0333x over previous
//
#include <hip/hip_runtime.h>
#include <hip/hip_fp16.h>

#define N_NODES 50000
#define N_EDGES 800000
#define N_GRAPHS 500
#define DIM 128
#define BN_EPS 1e-5f
#define CAP 64   // fixed per-node edge capacity (Poisson(16); P(deg>64) ~ 1e-20)

// ---- workspace word offsets (4-byte words). End = 12,961,088 w = 51.84 MB
// (proven-safe: ws_size >= 54.6 MB from R5 pass).
#define OFF_XB    0ull          // bf16 x copy        [3.2M words]
#define OFF_A0    3200000ull    // bf16 feat buf A    [3.2M words]
#define OFF_B1    6400000ull    // bf16 feat buf B    [3.2M words]
#define OFF_CUR   9600000ull    // per-node cursor    [N]
#define OFF_GST   9650000ull    // gstart             [G+1]
#define OFF_STATS 9650501ull    // bn stats x2        [512]
#define OFF_CSR   9720000ull    // packed bucketed CSR [N*CAP]
#define OFF_WB    12920000ull   // bf16 weights [2][128*128] -> 12,936,384
#define OFF_WC    12936384ull   // folded Wp@W2 f32   [16384]
#define OFF_BC    12952768ull   // folded bias f32    [128]

typedef unsigned short ushort_t;
typedef unsigned int uint_t;
typedef __attribute__((ext_vector_type(8))) short bf16x8;
typedef __attribute__((ext_vector_type(4))) float f32x4;

__device__ __forceinline__ float bf2f(uint_t u16) {
    return __uint_as_float(u16 << 16);
}
__device__ __forceinline__ ushort_t f2bf(float f) {
    uint_t x = __float_as_uint(f);
    uint_t r = (x + 0x7fffu + ((x >> 16) & 1u)) >> 16;   // round-to-nearest-even
    return (ushort_t)r;
}
__device__ __forceinline__ void unpack8(const uint4 v, float* f) {
    f[0] = bf2f(v.x & 0xffffu); f[1] = bf2f(v.x >> 16);
    f[2] = bf2f(v.y & 0xffffu); f[3] = bf2f(v.y >> 16);
    f[4] = bf2f(v.z & 0xffffu); f[5] = bf2f(v.z >> 16);
    f[6] = bf2f(v.w & 0xffffu); f[7] = bf2f(v.w >> 16);
}
__device__ __forceinline__ uint4 pack8(const float* f) {
    uint4 v;
    v.x = (uint_t)f2bf(f[0]) | ((uint_t)f2bf(f[1]) << 16);
    v.y = (uint_t)f2bf(f[2]) | ((uint_t)f2bf(f[3]) << 16);
    v.z = (uint_t)f2bf(f[4]) | ((uint_t)f2bf(f[5]) << 16);
    v.w = (uint_t)f2bf(f[6]) | ((uint_t)f2bf(f[7]) << 16);
    return v;
}

// ================= fused prep =================
// [0,3125): CSR fill (slot-interleaved); [3125,6250): x->bf16;
// [6250,6378): W0/W1->bf16; [6378,6574): pool boundaries; [6574]: zero stats;
// [6575,6640): Wc = Wp@W2 (f32) and bc = Wp@b2 + bp.
#define PREP_FILL_B 3125
#define PREP_XB_B   3125
#define PREP_WS_B   128
#define PREP_BD_B   196
#define PREP_WC_B   65
#define PREP_ST     (PREP_FILL_B + PREP_XB_B + PREP_WS_B + PREP_BD_B)
#define PREP_GRID   (PREP_ST + 1 + PREP_WC_B)

__global__ __launch_bounds__(256) void prep_kernel(
    const int* __restrict__ ei, const float* __restrict__ ew,
    const float* __restrict__ x, const int* __restrict__ batch,
    const float* __restrict__ W0, const float* __restrict__ W1,
    const float* __restrict__ W2, const float* __restrict__ b2,
    const float* __restrict__ Wp, const float* __restrict__ bp,
    int* __restrict__ cursor, uint_t* __restrict__ csr,
    ushort_t* __restrict__ xb, ushort_t* __restrict__ Wb,
    int* __restrict__ gstart, float* __restrict__ stats,
    float* __restrict__ Wc, float* __restrict__ bc) {
    int b = blockIdx.x;
    int tid = threadIdx.x;
    if (b < PREP_FILL_B) {
        int e = b * 256 + tid;
        if (e < N_EDGES) {
            int dst = ei[N_EDGES + e];
            int pos = atomicAdd(&cursor[dst], 1);
            if (pos < CAP) {
                // slot-interleaved remap: slot s = pos&3 owns contiguous
                // [s*16, s*16+16) so gather can uint4-load its 4 entries.
                int rpos = (pos & 3) * 16 + (pos >> 2);
                uint_t src = (uint_t)ei[e];
                uint_t wb = (uint_t)__half_as_ushort(__float2half(ew[e]));
                csr[(size_t)dst * CAP + rpos] = (src << 16) | wb;
            }
        }
    } else if (b < PREP_FILL_B + PREP_XB_B) {
        int i = (b - PREP_FILL_B) * 256 + tid;
        if (i < N_NODES * DIM / 8) {
            const float* p = x + (size_t)i * 8;
            float f[8];
            float4 a = *reinterpret_cast<const float4*>(p);
            float4 bb = *reinterpret_cast<const float4*>(p + 4);
            f[0]=a.x; f[1]=a.y; f[2]=a.z; f[3]=a.w;
            f[4]=bb.x; f[5]=bb.y; f[6]=bb.z; f[7]=bb.w;
            *reinterpret_cast<uint4*>(xb + (size_t)i * 8) = pack8(f);
        }
    } else if (b < PREP_FILL_B + PREP_XB_B + PREP_WS_B) {
        int i = (b - PREP_FILL_B - PREP_XB_B) * 256 + tid;
        if (i < 2 * DIM * DIM) {
            int layer = i >> 14;
            int idx = i & (DIM * DIM - 1);
            const float* Ws = (layer == 0) ? W0 : W1;
            Wb[(size_t)layer * DIM * DIM + idx] = f2bf(Ws[idx]);
        }
    } else if (b < PREP_ST) {
        int i = (b - PREP_FILL_B - PREP_XB_B - PREP_WS_B) * 256 + tid;
        if (i < N_NODES) {
            int bb = batch[i];
            if (i == 0) {
                for (int g = 0; g <= bb; ++g) gstart[g] = 0;
            } else {
                int pb = batch[i - 1];
                for (int g = pb + 1; g <= bb; ++g) gstart[g] = i;
            }
            if (i == N_NODES - 1) {
                for (int g = bb + 1; g <= N_GRAPHS; ++g) gstart[g] = N_NODES;
            }
        }
    } else if (b == PREP_ST) {
        // zero BOTH stats halves (512 words) with 256 threads
        stats[tid] = 0.0f;
        stats[tid + 256] = 0.0f;
    } else {
        // folded final projection: Wc = Wp @ W2, bc = Wp @ b2 + bp
        int idx = (b - PREP_ST - 1) * 256 + tid;
        if (idx < DIM * DIM) {
            int j = idx >> 7, i2 = idx & 127;
            const float* wpr = Wp + (size_t)j * DIM;
            float s = 0.0f;
            for (int k = 0; k < DIM; ++k)
                s += wpr[k] * W2[(size_t)k * DIM + i2];
            Wc[idx] = s;
        } else if (idx < DIM * DIM + DIM) {
            int j = idx - DIM * DIM;
            const float* wpr = Wp + (size_t)j * DIM;
            float s = bp[j];
            for (int k = 0; k < DIM; ++k) s += wpr[k] * b2[k];
            bc[j] = s;
        }
    }
}

// ================= fused gather + BN/ReLU + self term (free-running) ========
// One wave per dst: 4 edge slots x 16 lanes x 8 bf16. Slot s's edges are
// contiguous at bucket + s*16 (fill remap) -> uint4 csr loads.
__global__ __launch_bounds__(256) void aggr_gather_kernel(
    const ushort_t* __restrict__ h, const int* __restrict__ cursor,
    const uint_t* __restrict__ csr, const float* __restrict__ stats,
    const float* __restrict__ gamma, const float* __restrict__ beta,
    const float* __restrict__ eps_arr, int layer, int bn_flag,
    ushort_t* __restrict__ outA) {
    int wid = threadIdx.x >> 6;
    int lane = threadIdx.x & 63;
    int n = blockIdx.x * 4 + wid;
    if (n >= N_NODES) return;
    int q = lane & 15;
    int slot = lane >> 4;

    float scale[8], shift[8], floorv;
    if (bn_flag) {
        #pragma unroll
        for (int j = 0; j < 8; ++j) {
            int c = q * 8 + j;
            float mu = stats[c] * (1.0f / N_NODES);
            float var = stats[128 + c] * (1.0f / N_NODES) - mu * mu;
            float rstd = rsqrtf(var + BN_EPS);
            scale[j] = rstd * gamma[c];
            shift[j] = beta[c] - mu * scale[j];
        }
        floorv = 0.0f;
    } else {
        #pragma unroll
        for (int j = 0; j < 8; ++j) { scale[j] = 1.0f; shift[j] = 0.0f; }
        floorv = -3.0e38f;
    }

    int cnt = cursor[n];
    cnt = (cnt > CAP) ? CAP : cnt;
    int cnt_s = (cnt + 3 - slot) >> 2;            // this slot's entry count
    const uint_t* mycsr = csr + (size_t)n * CAP + slot * 16;
    float acc[8];
    #pragma unroll
    for (int j = 0; j < 8; ++j) acc[j] = 0.0f;

    int i = 0;
    for (; i + 4 <= cnt_s; i += 4) {
        uint4 u4 = *reinterpret_cast<const uint4*>(mycsr + i);
        int s0 = (int)(u4.x >> 16), s1 = (int)(u4.y >> 16);
        int s2 = (int)(u4.z >> 16), s3 = (int)(u4.w >> 16);
        uint4 v0 = *reinterpret_cast<const uint4*>(h + (size_t)s0 * DIM + q * 8);
        uint4 v1 = *reinterpret_cast<const uint4*>(h + (size_t)s1 * DIM + q * 8);
        uint4 v2 = *reinterpret_cast<const uint4*>(h + (size_t)s2 * DIM + q * 8);
        uint4 v3 = *reinterpret_cast<const uint4*>(h + (size_t)s3 * DIM + q * 8);
        float w0 = __half2float(__ushort_as_half((ushort_t)(u4.x & 0xffffu)));
        float w1 = __half2float(__ushort_as_half((ushort_t)(u4.y & 0xffffu)));
        float w2 = __half2float(__ushort_as_half((ushort_t)(u4.z & 0xffffu)));
        float w3 = __half2float(__ushort_as_half((ushort_t)(u4.w & 0xffffu)));
        float f0[8], f1[8], f2[8], f3[8];
        unpack8(v0, f0); unpack8(v1, f1); unpack8(v2, f2); unpack8(v3, f3);
        #pragma unroll
        for (int j = 0; j < 8; ++j) {
            acc[j] += fmaxf(f0[j] * scale[j] + shift[j], floorv) * w0;
            acc[j] += fmaxf(f1[j] * scale[j] + shift[j], floorv) * w1;
            acc[j] += fmaxf(f2[j] * scale[j] + shift[j], floorv) * w2;
            acc[j] += fmaxf(f3[j] * scale[j] + shift[j], floorv) * w3;
        }
    }
    for (; i < cnt_s; ++i) {
        uint_t u = mycsr[i];
        int s = (int)(u >> 16);
        float w = __half2float(__ushort_as_half((ushort_t)(u & 0xffffu)));
        uint4 v = *reinterpret_cast<const uint4*>(h + (size_t)s * DIM + q * 8);
        float f[8];
        unpack8(v, f);
        #pragma unroll
        for (int j = 0; j < 8; ++j)
            acc[j] += fmaxf(f[j] * scale[j] + shift[j], floorv) * w;
    }
    #pragma unroll
    for (int j = 0; j < 8; ++j) {
        acc[j] += __shfl_xor(acc[j], 16, 64);
        acc[j] += __shfl_xor(acc[j], 32, 64);
    }
    if (slot == 0) {
        float epsv = 1.0f + eps_arr[layer];
        uint4 hv = *reinterpret_cast<const uint4*>(h + (size_t)n * DIM + q * 8);
        float hf[8], o[8];
        unpack8(hv, hf);
        #pragma unroll
        for (int j = 0; j < 8; ++j) {
            float t = fmaxf(hf[j] * scale[j] + shift[j], floorv);
            o[j] = epsv * t + acc[j];
        }
        *reinterpret_cast<uint4*>(outA + (size_t)n * DIM + q * 8) = pack8(o);
    }
}

// ================= MFMA GEMM, W staged in LDS (fragment-interleaved) ========
// y = A @ W^T + b; single bf16 W, f32 accum. Block = 512 thr (8 waves),
// 128 rows; wave w owns m-tile w (its 16 rows only -> in-place safe, y == A).
// Wfrag[nt][kc][lane][8]: each ds_read_b128 is lane-consecutive -> no bank
// conflicts. do_stats: per-column sum/sumsq -> stats_out.
__global__ __launch_bounds__(512) void gin_gemm_mfma_kernel(
    const ushort_t* __restrict__ A, const ushort_t* __restrict__ Wb,
    const float* __restrict__ bias, int do_stats,
    ushort_t* __restrict__ y, float* __restrict__ stats_out) {
    __shared__ ushort_t Wfrag[8][4][64][8];   // 32 KB
    __shared__ float s_sum[128], s_sq[128];
    const int tid = threadIdx.x;

    // stage W -> LDS, fragment-interleaved (2048 uint4, 4 per thread)
    #pragma unroll
    for (int s = 0; s < 4; ++s) {
        int idx = tid + s * 512;
        int nt = idx >> 8;
        int kc = (idx >> 6) & 3;
        int L = idx & 63;
        int j = nt * 16 + (L & 15);
        int k0 = kc * 32 + (L >> 4) * 8;
        uint4 v = *reinterpret_cast<const uint4*>(Wb + (size_t)j * DIM + k0);
        *reinterpret_cast<uint4*>(&Wfrag[nt][kc][L][0]) = v;
    }
    if (do_stats && tid < 128) { s_sum[tid] = 0.0f; s_sq[tid] = 0.0f; }
    __syncthreads();

    const int w = tid >> 6;           // wave = m-tile 0..7
    const int lane = tid & 63;
    const int m = lane & 15;
    const int kg = lane >> 4;
    const int row = blockIdx.x * 128 + w * 16 + m;
    const bool valid = row < N_NODES;

    bf16x8 afrag[4];
    #pragma unroll
    for (int kc = 0; kc < 4; ++kc) {
        if (valid) {
            afrag[kc] = *reinterpret_cast<const bf16x8*>(
                A + (size_t)row * DIM + kc * 32 + kg * 8);
        } else {
            bf16x8 z;
            #pragma unroll
            for (int j = 0; j < 8; ++j) z[j] = 0;
            afrag[kc] = z;
        }
    }

    f32x4 acc[8];
    #pragma unroll
    for (int nt = 0; nt < 8; ++nt) acc[nt] = (f32x4){0.f, 0.f, 0.f, 0.f};

    #pragma unroll
    for (int nt = 0; nt < 8; ++nt) {
        #pragma unroll
        for (int kc = 0; kc < 4; ++kc) {
            bf16x8 bh = *reinterpret_cast<const bf16x8*>(&Wfrag[nt][kc][lane][0]);
            acc[nt] = __builtin_amdgcn_mfma_f32_16x16x32_bf16(afrag[kc], bh, acc[nt], 0, 0, 0);
        }
    }

    // C/D: col = lane&15, row = (lane>>4)*4 + reg
    const int orow0 = blockIdx.x * 128 + w * 16 + kg * 4;
    #pragma unroll
    for (int nt = 0; nt < 8; ++nt) {
        int c = nt * 16 + m;
        float bv = bias[c];
        float colsum = 0.0f, colsq = 0.0f;
        #pragma unroll
        for (int r = 0; r < 4; ++r) {
            int orow = orow0 + r;
            float val = acc[nt][r] + bv;
            if (orow < N_NODES) {
                y[(size_t)orow * DIM + c] = f2bf(val);
                colsum += val;
                colsq += val * val;
            }
        }
        if (do_stats) {
            colsum += __shfl_xor(colsum, 16, 64);
            colsq  += __shfl_xor(colsq, 16, 64);
            colsum += __shfl_xor(colsum, 32, 64);
            colsq  += __shfl_xor(colsq, 32, 64);
            if (kg == 0) {
                atomicAdd(&s_sum[c], colsum);
                atomicAdd(&s_sq[c], colsq);
            }
        }
    }
    if (do_stats) {
        __syncthreads();
        if (tid < 128) {
            unsafeAtomicAdd(&stats_out[tid], s_sum[tid]);
            unsafeAtomicAdd(&stats_out[128 + tid], s_sq[tid]);
        }
    }
}

// ================= fused pool (segmented mean of A2) + folded projection ====
// out = mean_g(A2) @ Wc^T + bc  (Wc = Wp@W2, bc = Wp@b2 + bp, f32)
__global__ __launch_bounds__(256) void poolfinal_kernel(
    const ushort_t* __restrict__ h, const int* __restrict__ gstart,
    const float* __restrict__ Wc, const float* __restrict__ bc,
    float* __restrict__ out) {
    __shared__ float sp[16][128];
    __shared__ float smean[128];
    int g = blockIdx.x;
    int colg = threadIdx.x & 15;
    int rslot = threadIdx.x >> 4;
    int s = gstart[g], e = gstart[g + 1];
    float acc[8];
    #pragma unroll
    for (int j = 0; j < 8; ++j) acc[j] = 0.0f;
    for (int r = s + rslot; r < e; r += 16) {
        uint4 v = *reinterpret_cast<const uint4*>(h + (size_t)r * DIM + colg * 8);
        float f[8];
        unpack8(v, f);
        #pragma unroll
        for (int j = 0; j < 8; ++j) acc[j] += f[j];
    }
    #pragma unroll
    for (int j = 0; j < 8; ++j) sp[rslot][colg * 8 + j] = acc[j];
    __syncthreads();
    if (threadIdx.x < 128) {
        int c = threadIdx.x;
        float a = 0.0f;
        #pragma unroll
        for (int k = 0; k < 16; ++k) a += sp[k][c];
        smean[c] = a / fmaxf((float)(e - s), 1.0f);
    }
    __syncthreads();
    if (threadIdx.x < 128) {
        int j = threadIdx.x;
        float o = bc[j];
        const float* wrow = Wc + (size_t)j * DIM;
        #pragma unroll
        for (int k = 0; k < DIM; k += 4) {
            float4 wv = *reinterpret_cast<const float4*>(wrow + k);
            o += smean[k] * wv.x + smean[k + 1] * wv.y
               + smean[k + 2] * wv.z + smean[k + 3] * wv.w;
        }
        out[(size_t)g * DIM + j] = o;
    }
}

extern "C" void kernel_launch(void* const* d_in, const int* in_sizes, int n_in,
                              void* d_out, int out_size, void* d_ws, size_t ws_size,
                              hipStream_t stream) {
    const int* ei = (const int*)d_in[0];
    const float* x = (const float*)d_in[1];
    const int* batch = (const int*)d_in[2];
    const float* ew = (const float*)d_in[3];
    const float* W0 = (const float*)d_in[4];
    const float* b0 = (const float*)d_in[5];
    const float* W1 = (const float*)d_in[6];
    const float* b1 = (const float*)d_in[7];
    const float* W2 = (const float*)d_in[8];
    const float* b2 = (const float*)d_in[9];
    const float* eps = (const float*)d_in[10];
    const float* bng = (const float*)d_in[11];
    const float* bnb = (const float*)d_in[12];
    const float* Wp = (const float*)d_in[13];
    const float* bp = (const float*)d_in[14];
    float* out = (float*)d_out;

    float* base = (float*)d_ws;
    ushort_t* XB = (ushort_t*)(base + OFF_XB);
    ushort_t* A0 = (ushort_t*)(base + OFF_A0);
    ushort_t* B1 = (ushort_t*)(base + OFF_B1);
    int* cursor = (int*)(base + OFF_CUR);
    int* gstart = (int*)(base + OFF_GST);
    float* stats0 = base + OFF_STATS;
    float* stats1 = stats0 + 256;
    uint_t* csr = (uint_t*)(base + OFF_CSR);
    ushort_t* Wb = (ushort_t*)(base + OFF_WB);
    float* Wc = base + OFF_WC;
    float* bc = base + OFF_BC;

    const int gatherGrid = (N_NODES + 3) / 4;
    const int mfmaGrid = (N_NODES + 127) / 128;   // 391 blocks x 512 threads
    const size_t wlayer = (size_t)DIM * DIM;

    hipMemsetAsync(cursor, 0, N_NODES * sizeof(int), stream);
    prep_kernel<<<PREP_GRID, 256, 0, stream>>>(
        ei, ew, x, batch, W0, W1, W2, b2, Wp, bp,
        cursor, csr, XB, Wb, gstart, stats0, Wc, bc);

    // layer 0 (no BN on input); stats of y -> stats0
    aggr_gather_kernel<<<gatherGrid, 256, 0, stream>>>(
        XB, cursor, csr, nullptr, nullptr, nullptr, eps, 0, 0, A0);
    gin_gemm_mfma_kernel<<<mfmaGrid, 512, 0, stream>>>(A0, Wb, b0, 1, A0, stats0);

    // layer 1 (BN0+ReLU fused into gather); stats of y -> stats1
    aggr_gather_kernel<<<gatherGrid, 256, 0, stream>>>(
        A0, cursor, csr, stats0, bng, bnb, eps, 1, 1, B1);
    gin_gemm_mfma_kernel<<<mfmaGrid, 512, 0, stream>>>(B1, Wb + wlayer, b1, 1, B1, stats1);

    // layer 2 (BN1+ReLU fused into gather) -> A2 matrix only; GEMM folded
    // into the pooled projection (pool is linear): out = mean(A2)@Wc^T + bc.
    aggr_gather_kernel<<<gatherGrid, 256, 0, stream>>>(
        B1, cursor, csr, stats1, bng + DIM, bnb + DIM, eps, 2, 1, A0);

    poolfinal_kernel<<<N_GRAPHS, 256, 0, stream>>>(A0, gstart, Wc, bc, out);
}